// Round 10
// baseline (192.059 us; speedup 1.0000x reference)
//
#include <hip/hip_runtime.h>
#include <hip/hip_fp16.h>
#include <math.h>

#define N_NODES 50000
#define N_EDGES 800000
#define F_IN    128
#define HID     64
#define HEADS   2
#define C1      128   // HEADS*HID
#define OUT_C   40
#define EDIM    5
#define NEG_SLOPE 0.2f
#define CAPN    64    // per-node LDS edge cache (Poisson(16): P(deg>64)~1e-20; fallback kept)
#define NPB1    16    // nodes per block, layer-1 agg (16 lanes/node)
#define NPB2    8     // nodes per block, layer-2 agg (32 lanes/node)
#define SCAN_B  256
#define SCAN_NB ((N_NODES + SCAN_B - 1) / SCAN_B)   // 196

// ---------------- workspace layout (element offsets, 4B units) ----------------
constexpr size_t pad64(size_t n){ return (n + 63) / 64 * 64; }
constexpr size_t O_CNT      = 0;
constexpr size_t O_ZERO_END = O_CNT      + pad64(N_NODES);
constexpr size_t O_RANK     = O_ZERO_END;
constexpr size_t O_ROWPTR   = O_RANK     + pad64(N_EDGES);
constexpr size_t O_STMP     = O_ROWPTR   + pad64(N_NODES+1);
constexpr size_t O_BSUM     = O_STMP     + pad64(N_NODES);
constexpr size_t O_BOFF     = O_BSUM     + pad64(SCAN_NB);
constexpr size_t O_EREC     = O_BOFF     + pad64(SCAN_NB);    // uint2 per edge {src|l2h, l0h|l1h}
constexpr size_t O_WEATT    = O_EREC     + pad64((size_t)N_EDGES*2);
constexpr size_t O_XHB      = O_WEATT    + 64;                       // bf16 [N][128]
constexpr size_t O_AS1      = O_XHB      + pad64((size_t)N_NODES*C1/2);
constexpr size_t O_AD1      = O_AS1      + pad64((size_t)N_NODES*2);
constexpr size_t O_H1       = O_AD1      + pad64((size_t)N_NODES*2);
constexpr size_t O_XH2B     = O_H1       + pad64((size_t)N_NODES*C1);  // bf16 [N][40]
constexpr size_t O_AS2      = O_XH2B     + pad64((size_t)N_NODES*OUT_C/2);
constexpr size_t O_AD2      = O_AS2      + pad64(N_NODES);

__device__ __forceinline__ float lrelu(float v){ return v >= 0.f ? v : NEG_SLOPE*v; }
__device__ __forceinline__ float bfl(unsigned u){ return __uint_as_float(u << 16); }
__device__ __forceinline__ float bfh(unsigned u){ return __uint_as_float(u & 0xFFFF0000u); }
__device__ __forceinline__ unsigned short f2bf(float f){
  unsigned u = __float_as_uint(f);
  return (unsigned short)((u + 0x7FFFu + ((u >> 16) & 1u)) >> 16);   // RNE
}
__device__ __forceinline__ unsigned f2h(float f){
  return (unsigned)__half_as_ushort(__float2half(f));
}
__device__ __forceinline__ float h2f(unsigned u){
  return __half2float(__ushort_as_half((unsigned short)(u & 0xFFFFu)));
}
__device__ __forceinline__ void fma8(float* acc, float e, uint4 r){
  acc[0] += e*bfl(r.x); acc[1] += e*bfh(r.x);
  acc[2] += e*bfl(r.y); acc[3] += e*bfh(r.y);
  acc[4] += e*bfl(r.z); acc[5] += e*bfh(r.z);
  acc[6] += e*bfl(r.w); acc[7] += e*bfh(r.w);
}

// ---------------- K0: tiny attention-projection matrices ----------------
__global__ void k_weatt(const float* __restrict__ We1, const float* __restrict__ ae1,
                        const float* __restrict__ We2, const float* __restrict__ ae2,
                        float* __restrict__ weatt){
  int t = threadIdx.x;
  if (t < 10){
    int k = t >> 1, h = t & 1;
    float s = 0.f;
    for (int c = 0; c < HID; c++) s += We1[k*C1 + h*HID + c] * ae1[h*HID + c];
    weatt[k*2 + h] = s;
  } else if (t < 15){
    int k = t - 10;
    float s = 0.f;
    for (int c = 0; c < OUT_C; c++) s += We2[k*OUT_C + c] * ae2[c];
    weatt[10 + k] = s;
  }
}

// ---------------- K1: in-degree + per-edge rank (atomic return value is free) ----------------
__global__ void k_count(const int* __restrict__ dst, int* __restrict__ cnt,
                        int* __restrict__ rank){
  int e = blockIdx.x*blockDim.x + threadIdx.x;
  if (e >= N_EDGES) return;
  rank[e] = atomicAdd(&cnt[dst[e]], 1);
}

// ---------------- K2: device-wide exclusive scan, 3 wide dispatches ----------------
__global__ void __launch_bounds__(SCAN_B) k_scan1(const int* __restrict__ cnt,
                                                  int* __restrict__ stmp,
                                                  int* __restrict__ bsum){
  int blk = blockIdx.x, t = threadIdx.x;
  int i = blk*SCAN_B + t;
  int v = (i < N_NODES) ? cnt[i] : 0;
  int lane = t & 63, w = t >> 6;
  int x = v;
  #pragma unroll
  for (int off = 1; off < 64; off <<= 1){
    int y = __shfl_up(x, off);
    if (lane >= off) x += y;
  }
  __shared__ int wsum[SCAN_B/64];
  if (lane == 63) wsum[w] = x;
  __syncthreads();
  int add = 0;
  for (int k = 0; k < w; k++) add += wsum[k];
  x += add;
  if (i < N_NODES) stmp[i] = x;
  if (t == SCAN_B-1) bsum[blk] = x;
}

__global__ void __launch_bounds__(SCAN_B) k_scan2(const int* __restrict__ bsum,
                                                  int* __restrict__ boff){
  int t = threadIdx.x;
  int v = (t < SCAN_NB) ? bsum[t] : 0;
  int lane = t & 63, w = t >> 6;
  int x = v;
  #pragma unroll
  for (int off = 1; off < 64; off <<= 1){
    int y = __shfl_up(x, off);
    if (lane >= off) x += y;
  }
  __shared__ int wsum[SCAN_B/64];
  if (lane == 63) wsum[w] = x;
  __syncthreads();
  int add = 0;
  for (int k = 0; k < w; k++) add += wsum[k];
  x += add;                      // inclusive
  if (t < SCAN_NB) boff[t] = x - v;  // exclusive
}

__global__ void __launch_bounds__(SCAN_B) k_scan3(const int* __restrict__ stmp,
                                                  const int* __restrict__ boff,
                                                  int* __restrict__ rowptr){
  int blk = blockIdx.x, t = threadIdx.x;
  int i = blk*SCAN_B + t;
  if (i < N_NODES) rowptr[i+1] = stmp[i] + boff[blk];
  if (i == 0) rowptr[0] = 0;
}

// ---------------- K3: scatter edges into CSR, atomic-free, 8B packed records ----------------
__global__ void k_scatter(const int* __restrict__ src, const int* __restrict__ dst,
                          const int* __restrict__ rank,
                          const float* __restrict__ eattr, const int* __restrict__ rowptr,
                          const float* __restrict__ weatt,
                          uint2* __restrict__ erec){
  int e = blockIdx.x*blockDim.x + threadIdx.x;
  if (e >= N_EDGES) return;
  int d = dst[e];
  int pos = rowptr[d] + rank[e];
  float a[EDIM];
  #pragma unroll
  for (int k = 0; k < EDIM; k++) a[k] = eattr[e*EDIM + k];
  float l0 = 0.f, l1 = 0.f, l2 = 0.f;
  #pragma unroll
  for (int k = 0; k < EDIM; k++){
    l0 += a[k]*weatt[k*2 + 0];
    l1 += a[k]*weatt[k*2 + 1];
    l2 += a[k]*weatt[10 + k];
  }
  unsigned w0 = (unsigned)src[e] | (f2h(l2) << 16);
  unsigned w1 = f2h(l0) | (f2h(l1) << 16);
  erec[pos] = make_uint2(w0, w1);
}

// ---------------- K5: xh1 = x @ W1 (register-tiled 128x128, fused att1, bf16 out) ----------------
#define T1_ROWS 128
#define T1_KK   32
__global__ void __launch_bounds__(256) k_gemm1(const float* __restrict__ x,
                                               const float* __restrict__ W,
                                               const float* __restrict__ a_src,
                                               const float* __restrict__ a_dst,
                                               unsigned short* __restrict__ xhb,
                                               float* __restrict__ as_o,
                                               float* __restrict__ ad_o){
  __shared__ float xs[T1_ROWS][T1_KK+1];
  __shared__ float ws[T1_KK][C1];
  int tid = threadIdx.x;
  int tx = tid & 15, ty = tid >> 4;
  int r0 = blockIdx.x * T1_ROWS;
  float acc[8][8];
  #pragma unroll
  for (int i = 0; i < 8; i++)
    #pragma unroll
    for (int j = 0; j < 8; j++) acc[i][j] = 0.f;

  for (int kb = 0; kb < F_IN; kb += T1_KK){
    __syncthreads();
    for (int i = tid; i < T1_ROWS*(T1_KK/4); i += 256){
      int r = i >> 3, c4 = (i & 7) * 4;
      int row = r0 + r;
      float4 v = (row < N_NODES) ? *(const float4*)&x[(size_t)row*F_IN + kb + c4]
                                 : make_float4(0.f,0.f,0.f,0.f);
      xs[r][c4+0]=v.x; xs[r][c4+1]=v.y; xs[r][c4+2]=v.z; xs[r][c4+3]=v.w;
    }
    for (int i = tid; i < T1_KK*(C1/4); i += 256){
      int k = i >> 5, c4 = (i & 31) * 4;
      *(float4*)&ws[k][c4] = *(const float4*)&W[(size_t)(kb + k)*C1 + c4];
    }
    __syncthreads();
    #pragma unroll 4
    for (int k = 0; k < T1_KK; k++){
      float a[8], b[8];
      #pragma unroll
      for (int i = 0; i < 8; i++) a[i] = xs[ty*8 + i][k];
      float4 b0 = *(const float4*)&ws[k][tx*8];
      float4 b1 = *(const float4*)&ws[k][tx*8+4];
      b[0]=b0.x; b[1]=b0.y; b[2]=b0.z; b[3]=b0.w;
      b[4]=b1.x; b[5]=b1.y; b[6]=b1.z; b[7]=b1.w;
      #pragma unroll
      for (int i = 0; i < 8; i++)
        #pragma unroll
        for (int j = 0; j < 8; j++)
          acc[i][j] += a[i]*b[j];
    }
  }
  float asv[8], adv[8];
  #pragma unroll
  for (int j = 0; j < 8; j++){
    asv[j] = a_src[tx*8 + j];
    adv[j] = a_dst[tx*8 + j];
  }
  int h = tx >> 3;
  #pragma unroll
  for (int i = 0; i < 8; i++){
    int row = r0 + ty*8 + i;
    bool ok = row < N_NODES;
    if (ok){
      unsigned short hh[8];
      #pragma unroll
      for (int j = 0; j < 8; j++) hh[j] = f2bf(acc[i][j]);
      uint4 pk;
      pk.x = (unsigned)hh[0] | ((unsigned)hh[1] << 16);
      pk.y = (unsigned)hh[2] | ((unsigned)hh[3] << 16);
      pk.z = (unsigned)hh[4] | ((unsigned)hh[5] << 16);
      pk.w = (unsigned)hh[6] | ((unsigned)hh[7] << 16);
      *(uint4*)&xhb[(size_t)row*C1 + tx*8] = pk;
    }
    float s = 0.f, d = 0.f;
    #pragma unroll
    for (int j = 0; j < 8; j++){ s += acc[i][j]*asv[j]; d += acc[i][j]*adv[j]; }
    s += __shfl_xor(s, 1); s += __shfl_xor(s, 2); s += __shfl_xor(s, 4);
    d += __shfl_xor(d, 1); d += __shfl_xor(d, 2); d += __shfl_xor(d, 4);
    if (ok && (tx & 7) == 0){
      as_o[row*2 + h] = s;
      ad_o[row*2 + h] = d;
    }
  }
}

// ---------------- K7: layer-1 aggregation; 16 lanes/node, 4-deep gather pipeline ----------------
__global__ void __launch_bounds__(256) k_agg1(const unsigned short* __restrict__ xhb,
    const int* __restrict__ rowptr, const uint2* __restrict__ erec,
    const float* __restrict__ as1, const float* __restrict__ ad1,
    const float* __restrict__ b1, float* __restrict__ h1){
  __shared__ float2 eC[NPB1][CAPN+1];   // interleaved (e0,e1) — padded row kills bank conflicts
  __shared__ int    sC[NPB1][CAPN+1];
  int t = threadIdx.x;
  int g = t >> 4, l = t & 15;
  int n = blockIdx.x*NPB1 + g;
  if (n >= N_NODES) return;
  int beg = rowptr[n], end = rowptr[n+1];
  int deg = end - beg;
  float2 adn = *(const float2*)&ad1[n*2];
  bool cached = (deg <= CAPN);

  // phase A: exp(logit) -> LDS (group-local), sums via 4-step shuffle
  float s0 = 0.f, s1 = 0.f, la0 = 0.f, la1 = 0.f;
  for (int i = l; i < deg; i += 16){
    uint2 r = erec[(size_t)beg + i];
    int s = r.x & 0xFFFFu;
    float al0 = h2f(r.y), al1 = h2f(r.y >> 16);
    float2 a = *(const float2*)&as1[s*2];
    float e0 = expf(lrelu(a.x + adn.x + al0));
    float e1 = expf(lrelu(a.y + adn.y + al1));
    if (cached){ sC[g][i] = s * C1; eC[g][i] = make_float2(e0, e1); }
    s0 += e0; s1 += e1; la0 += al0; la1 += al1;
  }
  #pragma unroll
  for (int off = 1; off < 16; off <<= 1){
    s0 += __shfl_xor(s0, off); s1 += __shfl_xor(s1, off);
    la0 += __shfl_xor(la0, off); la1 += __shfl_xor(la1, off);
  }
  float inv = 1.f / fmaxf((float)deg, 1.f);
  float2 asn = *(const float2*)&as1[n*2];
  float sl0 = lrelu(asn.x + adn.x + la0*inv);
  float sl1 = lrelu(asn.y + adn.y + la1*inv);
  float es0 = expf(sl0), es1 = expf(sl1);
  float S0 = s0 + es0 + 1e-16f;
  float S1 = s1 + es1 + 1e-16f;

  // phase B: 4 gathers in flight per lane, dual accumulator sets
  int head = l >> 3;                   // lane 0..7 head0 (cols 0..63), 8..15 head1
  float acc[8], acc2[8];
  #pragma unroll
  for (int j = 0; j < 8; j++){ acc[j] = 0.f; acc2[j] = 0.f; }
  if (cached){
    int k = 0;
    for (; k + 4 <= deg; k += 4){
      float2 ev0 = eC[g][k],   ev1 = eC[g][k+1];
      float2 ev2 = eC[g][k+2], ev3 = eC[g][k+3];
      uint4 r0 = *(const uint4*)&xhb[sC[g][k]   + l*8];
      uint4 r1 = *(const uint4*)&xhb[sC[g][k+1] + l*8];
      uint4 r2 = *(const uint4*)&xhb[sC[g][k+2] + l*8];
      uint4 r3 = *(const uint4*)&xhb[sC[g][k+3] + l*8];
      fma8(acc,  head ? ev0.y : ev0.x, r0);
      fma8(acc2, head ? ev1.y : ev1.x, r1);
      fma8(acc,  head ? ev2.y : ev2.x, r2);
      fma8(acc2, head ? ev3.y : ev3.x, r3);
    }
    for (; k < deg; k++){
      float2 ev = eC[g][k];
      uint4 r = *(const uint4*)&xhb[sC[g][k] + l*8];
      fma8(acc, head ? ev.y : ev.x, r);
    }
  } else {
    // fallback (deg > CAPN): recompute e per edge, group-local, ~never taken
    for (int k = 0; k < deg; k++){
      uint2 rr = erec[(size_t)beg + k];
      int s = rr.x & 0xFFFFu;
      float2 a = *(const float2*)&as1[s*2];
      float e = head ? expf(lrelu(a.y + adn.y + h2f(rr.y >> 16)))
                     : expf(lrelu(a.x + adn.x + h2f(rr.y)));
      uint4 r = *(const uint4*)&xhb[(size_t)s*C1 + l*8];
      fma8(acc, e, r);
    }
  }
  // epilogue: each lane owns its 8 cols — no cross-lane combine
  float es = head ? es1 : es0;
  float den = head ? S1 : S0;
  uint4 r = *(const uint4*)&xhb[(size_t)n*C1 + l*8];
  float xs8[8];
  xs8[0]=bfl(r.x); xs8[1]=bfh(r.x); xs8[2]=bfl(r.y); xs8[3]=bfh(r.y);
  xs8[4]=bfl(r.z); xs8[5]=bfh(r.z); xs8[6]=bfl(r.w); xs8[7]=bfh(r.w);
  float o[8];
  #pragma unroll
  for (int j = 0; j < 8; j++){
    float v = (acc[j] + acc2[j] + es*xs8[j]) / den + b1[l*8 + j];
    o[j] = v > 0.f ? v : expm1f(v);   // ELU
  }
  *(float4*)&h1[(size_t)n*C1 + l*8]     = make_float4(o[0],o[1],o[2],o[3]);
  *(float4*)&h1[(size_t)n*C1 + l*8 + 4] = make_float4(o[4],o[5],o[6],o[7]);
}

// ---------------- K8: xh2 = h1 @ W2 (register-tiled, fused att2, bf16 out) ----------------
#define T2_ROWS 128
#define T2_KK   32
__global__ void __launch_bounds__(256) k_gemm2(const float* __restrict__ h1,
    const float* __restrict__ W2, const float* __restrict__ a_src2,
    const float* __restrict__ a_dst2,
    unsigned short* __restrict__ xh2b, float* __restrict__ as_o, float* __restrict__ ad_o){
  __shared__ float hs[T2_ROWS][T2_KK+1];
  __shared__ float ws[F_IN*OUT_C];     // full W2, 20.5 KB
  int tid = threadIdx.x;
  int tx = tid & 7, ty = tid >> 3;     // tx: 8 col-groups of 5, ty: 32 row-groups of 4
  int r0 = blockIdx.x * T2_ROWS;
  for (int i = tid; i < F_IN*OUT_C/4; i += 256)
    ((float4*)ws)[i] = ((const float4*)W2)[i];
  float acc[4][5];
  #pragma unroll
  for (int i = 0; i < 4; i++)
    #pragma unroll
    for (int j = 0; j < 5; j++) acc[i][j] = 0.f;

  for (int kb = 0; kb < F_IN; kb += T2_KK){
    __syncthreads();
    for (int i = tid; i < T2_ROWS*(T2_KK/4); i += 256){
      int r = i >> 3, c4 = (i & 7) * 4;
      int row = r0 + r;
      float4 v = (row < N_NODES) ? *(const float4*)&h1[(size_t)row*F_IN + kb + c4]
                                 : make_float4(0.f,0.f,0.f,0.f);
      hs[r][c4+0]=v.x; hs[r][c4+1]=v.y; hs[r][c4+2]=v.z; hs[r][c4+3]=v.w;
    }
    __syncthreads();
    #pragma unroll 4
    for (int k = 0; k < T2_KK; k++){
      float a[4], b[5];
      #pragma unroll
      for (int i = 0; i < 4; i++) a[i] = hs[ty*4 + i][k];
      #pragma unroll
      for (int j = 0; j < 5; j++) b[j] = ws[(kb + k)*OUT_C + tx*5 + j];
      #pragma unroll
      for (int i = 0; i < 4; i++)
        #pragma unroll
        for (int j = 0; j < 5; j++)
          acc[i][j] += a[i]*b[j];
    }
  }
  float asv[5], adv[5];
  #pragma unroll
  for (int j = 0; j < 5; j++){
    asv[j] = a_src2[tx*5 + j];
    adv[j] = a_dst2[tx*5 + j];
  }
  #pragma unroll
  for (int i = 0; i < 4; i++){
    int row = r0 + ty*4 + i;
    bool ok = row < N_NODES;
    if (ok){
      #pragma unroll
      for (int j = 0; j < 5; j++)
        xh2b[(size_t)row*OUT_C + tx*5 + j] = f2bf(acc[i][j]);
    }
    float s = 0.f, d = 0.f;
    #pragma unroll
    for (int j = 0; j < 5; j++){ s += acc[i][j]*asv[j]; d += acc[i][j]*adv[j]; }
    s += __shfl_xor(s, 1); s += __shfl_xor(s, 2); s += __shfl_xor(s, 4);
    d += __shfl_xor(d, 1); d += __shfl_xor(d, 2); d += __shfl_xor(d, 4);
    if (ok && tx == 0){
      as_o[row] = s;
      ad_o[row] = d;
    }
  }
}

// ---------------- K10: layer-2 aggregation + log_softmax; 32 lanes/node, 4-deep gather ----------------
__global__ void __launch_bounds__(256) k_agg2(const unsigned short* __restrict__ xh2b,
    const int* __restrict__ rowptr, const uint2* __restrict__ erec,
    const float* __restrict__ as2, const float* __restrict__ ad2,
    const float* __restrict__ b2, float* __restrict__ out){
  __shared__ float eC[NPB2][CAPN+1];
  __shared__ int   sC[NPB2][CAPN+1];
  int t = threadIdx.x;
  int g = t >> 5, l = t & 31;
  int n = blockIdx.x*NPB2 + g;
  if (n >= N_NODES) return;
  int beg = rowptr[n], end = rowptr[n+1];
  int deg = end - beg;
  float adv = ad2[n];
  bool cached = (deg <= CAPN);

  // phase A
  float ss = 0.f, la = 0.f;
  for (int i = l; i < deg; i += 32){
    uint2 r = erec[(size_t)beg + i];
    int s = r.x & 0xFFFFu;
    float al2 = h2f(r.x >> 16);
    float e = expf(lrelu(as2[s] + adv + al2));
    if (cached){ sC[g][i] = s * OUT_C; eC[g][i] = e; }
    ss += e; la += al2;
  }
  #pragma unroll
  for (int off = 1; off < 32; off <<= 1){
    ss += __shfl_xor(ss, off);
    la += __shfl_xor(la, off);
  }
  float inv = 1.f / fmaxf((float)deg, 1.f);
  float sl = lrelu(as2[n] + adv + la*inv);
  float es = expf(sl);
  float S = ss + es + 1e-16f;

  // phase B: lanes 0..19 own cols {2l, 2l+1}; 4 gathers in flight, dual acc pairs
  float a0 = 0.f, a1 = 0.f, c0 = 0.f, c1 = 0.f;
  if (l < 20){
    if (cached){
      int k = 0;
      for (; k + 4 <= deg; k += 4){
        float e0 = eC[g][k],   e1 = eC[g][k+1];
        float e2 = eC[g][k+2], e3 = eC[g][k+3];
        unsigned u0 = *(const unsigned*)&xh2b[sC[g][k]   + l*2];
        unsigned u1 = *(const unsigned*)&xh2b[sC[g][k+1] + l*2];
        unsigned u2 = *(const unsigned*)&xh2b[sC[g][k+2] + l*2];
        unsigned u3 = *(const unsigned*)&xh2b[sC[g][k+3] + l*2];
        a0 += e0*bfl(u0); a1 += e0*bfh(u0);
        c0 += e1*bfl(u1); c1 += e1*bfh(u1);
        a0 += e2*bfl(u2); a1 += e2*bfh(u2);
        c0 += e3*bfl(u3); c1 += e3*bfh(u3);
      }
      for (; k < deg; k++){
        float e = eC[g][k];
        unsigned u = *(const unsigned*)&xh2b[sC[g][k] + l*2];
        a0 += e*bfl(u); a1 += e*bfh(u);
      }
      a0 += c0; a1 += c1;
    } else {
      for (int k = 0; k < deg; k++){
        uint2 rr = erec[(size_t)beg + k];
        int s = rr.x & 0xFFFFu;
        float e = expf(lrelu(as2[s] + adv + h2f(rr.x >> 16)));
        unsigned u = *(const unsigned*)&xh2b[(size_t)s*OUT_C + l*2];
        a0 += e*bfl(u); a1 += e*bfh(u);
      }
    }
  }
  float o0 = -INFINITY, o1 = -INFINITY;
  if (l < 20){
    unsigned u = *(const unsigned*)&xh2b[(size_t)n*OUT_C + l*2];
    o0 = (a0 + es*bfl(u)) / S + b2[l*2 + 0];
    o1 = (a1 + es*bfh(u)) / S + b2[l*2 + 1];
  }
  // log_softmax over 40 cols (2 per lane in lanes 0..19)
  float mm = fmaxf(o0, o1);
  #pragma unroll
  for (int off = 1; off < 32; off <<= 1) mm = fmaxf(mm, __shfl_xor(mm, off));
  float e = (l < 20) ? (expf(o0 - mm) + expf(o1 - mm)) : 0.f;
  #pragma unroll
  for (int off = 1; off < 32; off <<= 1) e += __shfl_xor(e, off);
  if (l < 20){
    float lse = logf(e);
    out[(size_t)n*OUT_C + l*2 + 0] = o0 - mm - lse;
    out[(size_t)n*OUT_C + l*2 + 1] = o1 - mm - lse;
  }
}

// ---------------- host launcher ----------------
extern "C" void kernel_launch(void* const* d_in, const int* in_sizes, int n_in,
                              void* d_out, int out_size, void* d_ws, size_t ws_size,
                              hipStream_t stream){
  const float* x        = (const float*)d_in[0];
  const int*   ei       = (const int*)  d_in[1];
  const float* eattr    = (const float*)d_in[2];
  const float* W1       = (const float*)d_in[3];
  const float* att_src1 = (const float*)d_in[4];
  const float* att_dst1 = (const float*)d_in[5];
  const float* We1      = (const float*)d_in[6];
  const float* att_e1   = (const float*)d_in[7];
  const float* b1       = (const float*)d_in[8];
  const float* W2       = (const float*)d_in[9];
  const float* att_src2 = (const float*)d_in[10];
  const float* att_dst2 = (const float*)d_in[11];
  const float* We2      = (const float*)d_in[12];
  const float* att_e2   = (const float*)d_in[13];
  const float* b2       = (const float*)d_in[14];
  const int* src = ei;
  const int* dst = ei + N_EDGES;

  float* wsf    = (float*)d_ws;
  int*   cnt     = (int*)(wsf + O_CNT);
  int*   rank    = (int*)(wsf + O_RANK);
  int*   rowptr  = (int*)(wsf + O_ROWPTR);
  int*   stmp    = (int*)(wsf + O_STMP);
  int*   bsum    = (int*)(wsf + O_BSUM);
  int*   boff    = (int*)(wsf + O_BOFF);
  uint2* erec    = (uint2*)(wsf + O_EREC);
  float* weatt   = wsf + O_WEATT;
  unsigned short* xhb  = (unsigned short*)(wsf + O_XHB);
  float* as1     = wsf + O_AS1;
  float* ad1     = wsf + O_AD1;
  float* h1      = wsf + O_H1;
  unsigned short* xh2b = (unsigned short*)(wsf + O_XH2B);
  float* as2     = wsf + O_AS2;
  float* ad2     = wsf + O_AD2;
  float* out     = (float*)d_out;

  hipMemsetAsync(wsf + O_CNT, 0, O_ZERO_END*sizeof(float), stream);

  const int EB = (N_EDGES + 255) / 256;

  k_weatt  <<<1, 64, 0, stream>>>(We1, att_e1, We2, att_e2, weatt);
  k_count  <<<EB, 256, 0, stream>>>(dst, cnt, rank);
  k_scan1  <<<SCAN_NB, SCAN_B, 0, stream>>>(cnt, stmp, bsum);
  k_scan2  <<<1, SCAN_B, 0, stream>>>(bsum, boff);
  k_scan3  <<<SCAN_NB, SCAN_B, 0, stream>>>(stmp, boff, rowptr);
  k_scatter<<<EB, 256, 0, stream>>>(src, dst, rank, eattr, rowptr, weatt, erec);

  k_gemm1  <<<(N_NODES + T1_ROWS - 1)/T1_ROWS, 256, 0, stream>>>(x, W1, att_src1, att_dst1,
                                                                 xhb, as1, ad1);
  k_agg1   <<<(N_NODES + NPB1 - 1)/NPB1, 256, 0, stream>>>(xhb, rowptr, erec, as1, ad1, b1, h1);

  k_gemm2  <<<(N_NODES + T2_ROWS - 1)/T2_ROWS, 256, 0, stream>>>(h1, W2, att_src2, att_dst2,
                                                                 xh2b, as2, ad2);
  k_agg2   <<<(N_NODES + NPB2 - 1)/NPB2, 256, 0, stream>>>(xh2b, rowptr, erec, as2, ad2, b2, out);
}

// Round 11
// 179.058 us; speedup vs baseline: 1.0726x; 1.0726x over previous
//
#include <hip/hip_runtime.h>
#include <hip/hip_fp16.h>
#include <math.h>

#define N_NODES 50000
#define N_EDGES 800000
#define F_IN    128
#define HID     64
#define HEADS   2
#define C1      128   // HEADS*HID
#define OUT_C   40
#define EDIM    5
#define NEG_SLOPE 0.2f
#define CAPN    64    // per-node LDS edge cache (Poisson(16): P(deg>64)~1e-20; fallback kept)
#define NPB1    16    // nodes per block, layer-1 agg (16 lanes/node)
#define NPB2    8     // nodes per block, layer-2 agg (32 lanes/node)
#define SCAN_B  256
#define SCAN_NB ((N_NODES + SCAN_B - 1) / SCAN_B)   // 196

typedef __bf16 bf16x8 __attribute__((ext_vector_type(8)));
typedef float  f32x4v __attribute__((ext_vector_type(4)));

// ---------------- workspace layout (element offsets, 4B units) ----------------
constexpr size_t pad64(size_t n){ return (n + 63) / 64 * 64; }
constexpr size_t O_CNT      = 0;
constexpr size_t O_ZERO_END = O_CNT      + pad64(N_NODES);
constexpr size_t O_RANK     = O_ZERO_END;
constexpr size_t O_ROWPTR   = O_RANK     + pad64(N_EDGES);
constexpr size_t O_STMP     = O_ROWPTR   + pad64(N_NODES+1);
constexpr size_t O_BSUM     = O_STMP     + pad64(N_NODES);
constexpr size_t O_BOFF     = O_BSUM     + pad64(SCAN_NB);
constexpr size_t O_EREC     = O_BOFF     + pad64(SCAN_NB);    // uint2 per edge {src|l2h, l0h|l1h}
constexpr size_t O_WEATT    = O_EREC     + pad64((size_t)N_EDGES*2);
constexpr size_t O_XHB      = O_WEATT    + 64;                       // bf16 [N][128]
constexpr size_t O_AS1      = O_XHB      + pad64((size_t)N_NODES*C1/2);
constexpr size_t O_AD1      = O_AS1      + pad64((size_t)N_NODES*2);
constexpr size_t O_H1       = O_AD1      + pad64((size_t)N_NODES*2);
constexpr size_t O_XH2B     = O_H1       + pad64((size_t)N_NODES*C1);  // bf16 [N][40]
constexpr size_t O_AS2      = O_XH2B     + pad64((size_t)N_NODES*OUT_C/2);
constexpr size_t O_AD2      = O_AS2      + pad64(N_NODES);

__device__ __forceinline__ float lrelu(float v){ return v >= 0.f ? v : NEG_SLOPE*v; }
__device__ __forceinline__ float bfl(unsigned u){ return __uint_as_float(u << 16); }
__device__ __forceinline__ float bfh(unsigned u){ return __uint_as_float(u & 0xFFFF0000u); }
__device__ __forceinline__ unsigned short f2bf(float f){
  unsigned u = __float_as_uint(f);
  return (unsigned short)((u + 0x7FFFu + ((u >> 16) & 1u)) >> 16);   // RNE
}
__device__ __forceinline__ unsigned f2h(float f){
  return (unsigned)__half_as_ushort(__float2half(f));
}
__device__ __forceinline__ float h2f(unsigned u){
  return __half2float(__ushort_as_half((unsigned short)(u & 0xFFFFu)));
}

// ---------------- K1: in-degree + per-edge rank (atomic return value is free) ----------------
__global__ void k_count(const int* __restrict__ dst, int* __restrict__ cnt,
                        int* __restrict__ rank){
  int e = blockIdx.x*blockDim.x + threadIdx.x;
  if (e >= N_EDGES) return;
  rank[e] = atomicAdd(&cnt[dst[e]], 1);
}

// ---------------- K2: device-wide exclusive scan, 3 wide dispatches ----------------
__global__ void __launch_bounds__(SCAN_B) k_scan1(const int* __restrict__ cnt,
                                                  int* __restrict__ stmp,
                                                  int* __restrict__ bsum){
  int blk = blockIdx.x, t = threadIdx.x;
  int i = blk*SCAN_B + t;
  int v = (i < N_NODES) ? cnt[i] : 0;
  int lane = t & 63, w = t >> 6;
  int x = v;
  #pragma unroll
  for (int off = 1; off < 64; off <<= 1){
    int y = __shfl_up(x, off);
    if (lane >= off) x += y;
  }
  __shared__ int wsum[SCAN_B/64];
  if (lane == 63) wsum[w] = x;
  __syncthreads();
  int add = 0;
  for (int k = 0; k < w; k++) add += wsum[k];
  x += add;
  if (i < N_NODES) stmp[i] = x;
  if (t == SCAN_B-1) bsum[blk] = x;
}

// scan2 + fused weatt (tiny attention-projection matrices) — saves a dispatch
__global__ void __launch_bounds__(SCAN_B) k_scan2(const int* __restrict__ bsum,
                                                  int* __restrict__ boff,
                                                  const float* __restrict__ We1,
                                                  const float* __restrict__ ae1,
                                                  const float* __restrict__ We2,
                                                  const float* __restrict__ ae2,
                                                  float* __restrict__ weatt){
  int t = threadIdx.x;
  int v = (t < SCAN_NB) ? bsum[t] : 0;
  int lane = t & 63, w = t >> 6;
  int x = v;
  #pragma unroll
  for (int off = 1; off < 64; off <<= 1){
    int y = __shfl_up(x, off);
    if (lane >= off) x += y;
  }
  __shared__ int wsum[SCAN_B/64];
  if (lane == 63) wsum[w] = x;
  __syncthreads();
  int add = 0;
  for (int k = 0; k < w; k++) add += wsum[k];
  x += add;                      // inclusive
  if (t < SCAN_NB) boff[t] = x - v;  // exclusive
  // weatt: weatt[k*2+h] = sum_c We1[k,h*64+c]*ae1[h,c]; weatt[10+k] = sum_c We2[k,c]*ae2[c]
  if (t < 10){
    int k = t >> 1, h = t & 1;
    float s = 0.f;
    for (int c = 0; c < HID; c++) s += We1[k*C1 + h*HID + c] * ae1[h*HID + c];
    weatt[k*2 + h] = s;
  } else if (t < 15){
    int k = t - 10;
    float s = 0.f;
    for (int c = 0; c < OUT_C; c++) s += We2[k*OUT_C + c] * ae2[c];
    weatt[10 + k] = s;
  }
}

__global__ void __launch_bounds__(SCAN_B) k_scan3(const int* __restrict__ stmp,
                                                  const int* __restrict__ boff,
                                                  int* __restrict__ rowptr){
  int blk = blockIdx.x, t = threadIdx.x;
  int i = blk*SCAN_B + t;
  if (i < N_NODES) rowptr[i+1] = stmp[i] + boff[blk];
  if (i == 0) rowptr[0] = 0;
}

// ---------------- K3: scatter edges into CSR, atomic-free, 8B packed records ----------------
__global__ void k_scatter(const int* __restrict__ src, const int* __restrict__ dst,
                          const int* __restrict__ rank,
                          const float* __restrict__ eattr, const int* __restrict__ rowptr,
                          const float* __restrict__ weatt,
                          uint2* __restrict__ erec){
  int e = blockIdx.x*blockDim.x + threadIdx.x;
  if (e >= N_EDGES) return;
  int d = dst[e];
  int pos = rowptr[d] + rank[e];
  float a[EDIM];
  #pragma unroll
  for (int k = 0; k < EDIM; k++) a[k] = eattr[e*EDIM + k];
  float l0 = 0.f, l1 = 0.f, l2 = 0.f;
  #pragma unroll
  for (int k = 0; k < EDIM; k++){
    l0 += a[k]*weatt[k*2 + 0];
    l1 += a[k]*weatt[k*2 + 1];
    l2 += a[k]*weatt[10 + k];
  }
  unsigned w0 = (unsigned)src[e] | (f2h(l2) << 16);
  unsigned w1 = f2h(l0) | (f2h(l1) << 16);
  erec[pos] = make_uint2(w0, w1);
}

// ---------------- K5: xh1 = x @ W1 via MFMA bf16 (fused att1, bf16 out) ----------------
// 64 rows/block, 4 waves x 16 rows; K=128 in 4 steps of 32; 8 col-tiles of 16.
// Operand k-mapping: elem e of lane-group g (=lane>>4) covers k = 8g+e for BOTH A and B
// (any consistent bijection is valid); C/D layout: col=lane&15, row=4*(lane>>4)+reg (HW-verified).
__global__ void __launch_bounds__(256) k_gemm1(const float* __restrict__ x,
                                               const float* __restrict__ W,
                                               const float* __restrict__ a_src,
                                               const float* __restrict__ a_dst,
                                               unsigned short* __restrict__ xhb,
                                               float* __restrict__ as_o,
                                               float* __restrict__ ad_o){
  __shared__ __align__(16) unsigned char smem[128*136*2];     // 34816 B
  __bf16 (*wt)[136] = (__bf16(*)[136])smem;                   // W^T bf16: wt[col][k]
  float  (*eps)[132] = (float(*)[132])smem;                   // epilogue f32 [64][132] (33792 B)
  int tid = threadIdx.x;
  int wv = tid >> 6, L = tid & 63;
  int g = L >> 4, c16 = L & 15;
  int r0 = blockIdx.x * 64;

  // stage W^T as bf16 (one-time per block)
  for (int i = tid; i < F_IN*C1; i += 256){
    int k = i >> 7, c = i & 127;
    wt[c][k] = (__bf16)W[i];
  }
  __syncthreads();

  f32x4v acc[8];
  #pragma unroll
  for (int ct = 0; ct < 8; ct++) acc[ct] = (f32x4v){0.f, 0.f, 0.f, 0.f};

  int arow = r0 + wv*16 + c16;
  bool aok = arow < N_NODES;
  const float* xrow = &x[(size_t)arow*F_IN];
  #pragma unroll
  for (int ks = 0; ks < 4; ks++){
    int k0 = ks*32 + g*8;
    bf16x8 a;
    if (aok){
      float4 v0 = *(const float4*)&xrow[k0];
      float4 v1 = *(const float4*)&xrow[k0 + 4];
      a[0]=(__bf16)v0.x; a[1]=(__bf16)v0.y; a[2]=(__bf16)v0.z; a[3]=(__bf16)v0.w;
      a[4]=(__bf16)v1.x; a[5]=(__bf16)v1.y; a[6]=(__bf16)v1.z; a[7]=(__bf16)v1.w;
    } else {
      a = (bf16x8)(__bf16)0.f;
    }
    #pragma unroll
    for (int ct = 0; ct < 8; ct++){
      bf16x8 b = *(const bf16x8*)&wt[ct*16 + c16][k0];
      acc[ct] = __builtin_amdgcn_mfma_f32_16x16x32_bf16(a, b, acc[ct], 0, 0, 0);
    }
  }
  __syncthreads();   // all wt reads done; reuse LDS as epilogue buffer

  #pragma unroll
  for (int ct = 0; ct < 8; ct++){
    #pragma unroll
    for (int r = 0; r < 4; r++)
      eps[wv*16 + g*4 + r][ct*16 + c16] = acc[ct][r];
  }
  __syncthreads();

  // readout: thread t -> row t>>2, 32-col block (t&3); coalesced bf16 store + fused att dots
  int row = tid >> 2, cb = tid & 3;
  int grow = r0 + row;
  float vals[32];
  #pragma unroll
  for (int j = 0; j < 32; j++) vals[j] = eps[row][cb*32 + j];
  if (grow < N_NODES){
    unsigned pk[16];
    #pragma unroll
    for (int j = 0; j < 16; j++)
      pk[j] = (unsigned)f2bf(vals[2*j]) | ((unsigned)f2bf(vals[2*j+1]) << 16);
    uint4* d4 = (uint4*)&xhb[(size_t)grow*C1 + cb*32];
    d4[0] = make_uint4(pk[0],pk[1],pk[2],pk[3]);
    d4[1] = make_uint4(pk[4],pk[5],pk[6],pk[7]);
    d4[2] = make_uint4(pk[8],pk[9],pk[10],pk[11]);
    d4[3] = make_uint4(pk[12],pk[13],pk[14],pk[15]);
  }
  float s = 0.f, d = 0.f;
  #pragma unroll
  for (int j = 0; j < 32; j++){
    s += vals[j]*a_src[cb*32 + j];
    d += vals[j]*a_dst[cb*32 + j];
  }
  s += __shfl_xor(s, 1);
  d += __shfl_xor(d, 1);
  if ((cb & 1) == 0 && grow < N_NODES){
    int h = cb >> 1;
    as_o[grow*2 + h] = s;
    ad_o[grow*2 + h] = d;
  }
}

// ---------------- K7: layer-1 aggregation; 16 lanes per node, no barriers ----------------
__global__ void __launch_bounds__(256) k_agg1(const unsigned short* __restrict__ xhb,
    const int* __restrict__ rowptr, const uint2* __restrict__ erec,
    const float* __restrict__ as1, const float* __restrict__ ad1,
    const float* __restrict__ b1, float* __restrict__ h1){
  __shared__ float2 eC[NPB1][CAPN+1];   // interleaved (e0,e1) — padded row kills bank conflicts
  __shared__ int    sC[NPB1][CAPN+1];
  int t = threadIdx.x;
  int g = t >> 4, l = t & 15;
  int n = blockIdx.x*NPB1 + g;
  if (n >= N_NODES) return;
  int beg = rowptr[n], end = rowptr[n+1];
  int deg = end - beg;
  float2 adn = *(const float2*)&ad1[n*2];
  bool cached = (deg <= CAPN);

  // phase A: exp(logit) -> LDS (group-local), sums via 4-step shuffle
  float s0 = 0.f, s1 = 0.f, la0 = 0.f, la1 = 0.f;
  for (int i = l; i < deg; i += 16){
    uint2 r = erec[(size_t)beg + i];
    int s = r.x & 0xFFFFu;
    float al0 = h2f(r.y), al1 = h2f(r.y >> 16);
    float2 a = *(const float2*)&as1[s*2];
    float e0 = expf(lrelu(a.x + adn.x + al0));
    float e1 = expf(lrelu(a.y + adn.y + al1));
    if (cached){ sC[g][i] = s * C1; eC[g][i] = make_float2(e0, e1); }
    s0 += e0; s1 += e1; la0 += al0; la1 += al1;
  }
  #pragma unroll
  for (int off = 1; off < 16; off <<= 1){
    s0 += __shfl_xor(s0, off); s1 += __shfl_xor(s1, off);
    la0 += __shfl_xor(la0, off); la1 += __shfl_xor(la1, off);
  }
  float inv = 1.f / fmaxf((float)deg, 1.f);
  float2 asn = *(const float2*)&as1[n*2];
  float sl0 = lrelu(asn.x + adn.x + la0*inv);
  float sl1 = lrelu(asn.y + adn.y + la1*inv);
  float es0 = expf(sl0), es1 = expf(sl1);
  float S0 = s0 + es0 + 1e-16f;
  float S1 = s1 + es1 + 1e-16f;

  // phase B: per edge — e broadcast from LDS, 16 lanes x 16B coalesced row
  int head = l >> 3;                   // lane 0..7 head0 (cols 0..63), 8..15 head1
  float acc[8];
  #pragma unroll
  for (int j = 0; j < 8; j++) acc[j] = 0.f;
  if (cached){
    for (int k = 0; k < deg; k++){
      float2 e2 = eC[g][k];
      float e = head ? e2.y : e2.x;
      uint4 r = *(const uint4*)&xhb[sC[g][k] + l*8];
      acc[0] += e*bfl(r.x); acc[1] += e*bfh(r.x);
      acc[2] += e*bfl(r.y); acc[3] += e*bfh(r.y);
      acc[4] += e*bfl(r.z); acc[5] += e*bfh(r.z);
      acc[6] += e*bfl(r.w); acc[7] += e*bfh(r.w);
    }
  } else {
    // fallback (deg > CAPN): recompute e per edge, group-local, ~never taken
    for (int k = 0; k < deg; k++){
      uint2 rr = erec[(size_t)beg + k];
      int s = rr.x & 0xFFFFu;
      float2 a = *(const float2*)&as1[s*2];
      float e = head ? expf(lrelu(a.y + adn.y + h2f(rr.y >> 16)))
                     : expf(lrelu(a.x + adn.x + h2f(rr.y)));
      uint4 r = *(const uint4*)&xhb[(size_t)s*C1 + l*8];
      acc[0] += e*bfl(r.x); acc[1] += e*bfh(r.x);
      acc[2] += e*bfl(r.y); acc[3] += e*bfh(r.y);
      acc[4] += e*bfl(r.z); acc[5] += e*bfh(r.z);
      acc[6] += e*bfl(r.w); acc[7] += e*bfh(r.w);
    }
  }
  // epilogue: each lane owns its 8 cols — no cross-lane combine
  float es = head ? es1 : es0;
  float den = head ? S1 : S0;
  uint4 r = *(const uint4*)&xhb[(size_t)n*C1 + l*8];
  float xs8[8];
  xs8[0]=bfl(r.x); xs8[1]=bfh(r.x); xs8[2]=bfl(r.y); xs8[3]=bfh(r.y);
  xs8[4]=bfl(r.z); xs8[5]=bfh(r.z); xs8[6]=bfl(r.w); xs8[7]=bfh(r.w);
  float o[8];
  #pragma unroll
  for (int j = 0; j < 8; j++){
    float v = (acc[j] + es*xs8[j]) / den + b1[l*8 + j];
    o[j] = v > 0.f ? v : expm1f(v);   // ELU
  }
  *(float4*)&h1[(size_t)n*C1 + l*8]     = make_float4(o[0],o[1],o[2],o[3]);
  *(float4*)&h1[(size_t)n*C1 + l*8 + 4] = make_float4(o[4],o[5],o[6],o[7]);
}

// ---------------- K8: xh2 = h1 @ W2 (register-tiled, fused att2, bf16 out) ----------------
#define T2_ROWS 128
#define T2_KK   32
__global__ void __launch_bounds__(256) k_gemm2(const float* __restrict__ h1,
    const float* __restrict__ W2, const float* __restrict__ a_src2,
    const float* __restrict__ a_dst2,
    unsigned short* __restrict__ xh2b, float* __restrict__ as_o, float* __restrict__ ad_o){
  __shared__ float hs[T2_ROWS][T2_KK+1];
  __shared__ float ws[F_IN*OUT_C];     // full W2, 20.5 KB
  int tid = threadIdx.x;
  int tx = tid & 7, ty = tid >> 3;     // tx: 8 col-groups of 5, ty: 32 row-groups of 4
  int r0 = blockIdx.x * T2_ROWS;
  for (int i = tid; i < F_IN*OUT_C/4; i += 256)
    ((float4*)ws)[i] = ((const float4*)W2)[i];
  float acc[4][5];
  #pragma unroll
  for (int i = 0; i < 4; i++)
    #pragma unroll
    for (int j = 0; j < 5; j++) acc[i][j] = 0.f;

  for (int kb = 0; kb < F_IN; kb += T2_KK){
    __syncthreads();
    for (int i = tid; i < T2_ROWS*(T2_KK/4); i += 256){
      int r = i >> 3, c4 = (i & 7) * 4;
      int row = r0 + r;
      float4 v = (row < N_NODES) ? *(const float4*)&h1[(size_t)row*F_IN + kb + c4]
                                 : make_float4(0.f,0.f,0.f,0.f);
      hs[r][c4+0]=v.x; hs[r][c4+1]=v.y; hs[r][c4+2]=v.z; hs[r][c4+3]=v.w;
    }
    __syncthreads();
    #pragma unroll 4
    for (int k = 0; k < T2_KK; k++){
      float a[4], b[5];
      #pragma unroll
      for (int i = 0; i < 4; i++) a[i] = hs[ty*4 + i][k];
      #pragma unroll
      for (int j = 0; j < 5; j++) b[j] = ws[(kb + k)*OUT_C + tx*5 + j];
      #pragma unroll
      for (int i = 0; i < 4; i++)
        #pragma unroll
        for (int j = 0; j < 5; j++)
          acc[i][j] += a[i]*b[j];
    }
  }
  float asv[5], adv[5];
  #pragma unroll
  for (int j = 0; j < 5; j++){
    asv[j] = a_src2[tx*5 + j];
    adv[j] = a_dst2[tx*5 + j];
  }
  #pragma unroll
  for (int i = 0; i < 4; i++){
    int row = r0 + ty*4 + i;
    bool ok = row < N_NODES;
    if (ok){
      #pragma unroll
      for (int j = 0; j < 5; j++)
        xh2b[(size_t)row*OUT_C + tx*5 + j] = f2bf(acc[i][j]);
    }
    float s = 0.f, d = 0.f;
    #pragma unroll
    for (int j = 0; j < 5; j++){ s += acc[i][j]*asv[j]; d += acc[i][j]*adv[j]; }
    s += __shfl_xor(s, 1); s += __shfl_xor(s, 2); s += __shfl_xor(s, 4);
    d += __shfl_xor(d, 1); d += __shfl_xor(d, 2); d += __shfl_xor(d, 4);
    if (ok && tx == 0){
      as_o[row] = s;
      ad_o[row] = d;
    }
  }
}

// ---------------- K10: layer-2 aggregation + log_softmax; 32 lanes per node ----------------
__global__ void __launch_bounds__(256) k_agg2(const unsigned short* __restrict__ xh2b,
    const int* __restrict__ rowptr, const uint2* __restrict__ erec,
    const float* __restrict__ as2, const float* __restrict__ ad2,
    const float* __restrict__ b2, float* __restrict__ out){
  __shared__ float eC[NPB2][CAPN+1];
  __shared__ int   sC[NPB2][CAPN+1];
  int t = threadIdx.x;
  int g = t >> 5, l = t & 31;
  int n = blockIdx.x*NPB2 + g;
  if (n >= N_NODES) return;
  int beg = rowptr[n], end = rowptr[n+1];
  int deg = end - beg;
  float adv = ad2[n];
  bool cached = (deg <= CAPN);

  // phase A
  float ss = 0.f, la = 0.f;
  for (int i = l; i < deg; i += 32){
    uint2 r = erec[(size_t)beg + i];
    int s = r.x & 0xFFFFu;
    float al2 = h2f(r.x >> 16);
    float e = expf(lrelu(as2[s] + adv + al2));
    if (cached){ sC[g][i] = s * OUT_C; eC[g][i] = e; }
    ss += e; la += al2;
  }
  #pragma unroll
  for (int off = 1; off < 32; off <<= 1){
    ss += __shfl_xor(ss, off);
    la += __shfl_xor(la, off);
  }
  float inv = 1.f / fmaxf((float)deg, 1.f);
  float sl = lrelu(as2[n] + adv + la*inv);
  float es = expf(sl);
  float S = ss + es + 1e-16f;

  // phase B: lanes 0..19 own cols {2l, 2l+1}
  float a0 = 0.f, a1 = 0.f;
  if (l < 20){
    if (cached){
      for (int k = 0; k < deg; k++){
        float e = eC[g][k];
        unsigned u = *(const unsigned*)&xh2b[sC[g][k] + l*2];
        a0 += e*bfl(u); a1 += e*bfh(u);
      }
    } else {
      for (int k = 0; k < deg; k++){
        uint2 rr = erec[(size_t)beg + k];
        int s = rr.x & 0xFFFFu;
        float e = expf(lrelu(as2[s] + adv + h2f(rr.x >> 16)));
        unsigned u = *(const unsigned*)&xh2b[(size_t)s*OUT_C + l*2];
        a0 += e*bfl(u); a1 += e*bfh(u);
      }
    }
  }
  float o0 = -INFINITY, o1 = -INFINITY;
  if (l < 20){
    unsigned u = *(const unsigned*)&xh2b[(size_t)n*OUT_C + l*2];
    o0 = (a0 + es*bfl(u)) / S + b2[l*2 + 0];
    o1 = (a1 + es*bfh(u)) / S + b2[l*2 + 1];
  }
  // log_softmax over 40 cols (2 per lane in lanes 0..19)
  float mm = fmaxf(o0, o1);
  #pragma unroll
  for (int off = 1; off < 32; off <<= 1) mm = fmaxf(mm, __shfl_xor(mm, off));
  float e = (l < 20) ? (expf(o0 - mm) + expf(o1 - mm)) : 0.f;
  #pragma unroll
  for (int off = 1; off < 32; off <<= 1) e += __shfl_xor(e, off);
  if (l < 20){
    float lse = logf(e);
    out[(size_t)n*OUT_C + l*2 + 0] = o0 - mm - lse;
    out[(size_t)n*OUT_C + l*2 + 1] = o1 - mm - lse;
  }
}

// ---------------- host launcher ----------------
extern "C" void kernel_launch(void* const* d_in, const int* in_sizes, int n_in,
                              void* d_out, int out_size, void* d_ws, size_t ws_size,
                              hipStream_t stream){
  const float* x        = (const float*)d_in[0];
  const int*   ei       = (const int*)  d_in[1];
  const float* eattr    = (const float*)d_in[2];
  const float* W1       = (const float*)d_in[3];
  const float* att_src1 = (const float*)d_in[4];
  const float* att_dst1 = (const float*)d_in[5];
  const float* We1      = (const float*)d_in[6];
  const float* att_e1   = (const float*)d_in[7];
  const float* b1       = (const float*)d_in[8];
  const float* W2       = (const float*)d_in[9];
  const float* att_src2 = (const float*)d_in[10];
  const float* att_dst2 = (const float*)d_in[11];
  const float* We2      = (const float*)d_in[12];
  const float* att_e2   = (const float*)d_in[13];
  const float* b2       = (const float*)d_in[14];
  const int* src = ei;
  const int* dst = ei + N_EDGES;

  float* wsf    = (float*)d_ws;
  int*   cnt     = (int*)(wsf + O_CNT);
  int*   rank    = (int*)(wsf + O_RANK);
  int*   rowptr  = (int*)(wsf + O_ROWPTR);
  int*   stmp    = (int*)(wsf + O_STMP);
  int*   bsum    = (int*)(wsf + O_BSUM);
  int*   boff    = (int*)(wsf + O_BOFF);
  uint2* erec    = (uint2*)(wsf + O_EREC);
  float* weatt   = wsf + O_WEATT;
  unsigned short* xhb  = (unsigned short*)(wsf + O_XHB);
  float* as1     = wsf + O_AS1;
  float* ad1     = wsf + O_AD1;
  float* h1      = wsf + O_H1;
  unsigned short* xh2b = (unsigned short*)(wsf + O_XH2B);
  float* as2     = wsf + O_AS2;
  float* ad2     = wsf + O_AD2;
  float* out     = (float*)d_out;

  hipMemsetAsync(wsf + O_CNT, 0, O_ZERO_END*sizeof(float), stream);

  const int EB = (N_EDGES + 255) / 256;

  k_count  <<<EB, 256, 0, stream>>>(dst, cnt, rank);
  k_scan1  <<<SCAN_NB, SCAN_B, 0, stream>>>(cnt, stmp, bsum);
  k_scan2  <<<1, SCAN_B, 0, stream>>>(bsum, boff, We1, att_e1, We2, att_e2, weatt);
  k_scan3  <<<SCAN_NB, SCAN_B, 0, stream>>>(stmp, boff, rowptr);
  k_scatter<<<EB, 256, 0, stream>>>(src, dst, rank, eattr, rowptr, weatt, erec);

  k_gemm1  <<<(N_NODES + 63)/64, 256, 0, stream>>>(x, W1, att_src1, att_dst1, xhb, as1, ad1);
  k_agg1   <<<(N_NODES + NPB1 - 1)/NPB1, 256, 0, stream>>>(xhb, rowptr, erec, as1, ad1, b1, h1);

  k_gemm2  <<<(N_NODES + T2_ROWS - 1)/T2_ROWS, 256, 0, stream>>>(h1, W2, att_src2, att_dst2,
                                                                 xh2b, as2, ad2);
  k_agg2   <<<(N_NODES + NPB2 - 1)/NPB2, 256, 0, stream>>>(xh2b, rowptr, erec, as2, ad2, b2, out);
}

// Round 12
// 167.722 us; speedup vs baseline: 1.1451x; 1.0676x over previous
//
#include <hip/hip_runtime.h>
#include <hip/hip_fp16.h>
#include <math.h>

#define N_NODES 50000
#define N_EDGES 800000
#define F_IN    128
#define HID     64
#define HEADS   2
#define C1      128   // HEADS*HID
#define OUT_C   40
#define EDIM    5
#define NEG_SLOPE 0.2f
#define CAPN    64    // per-node LDS edge cache (Poisson(16): P(deg>64)~1e-20; fallback kept)
#define NPB1    16    // nodes per block, layer-1 agg (16 lanes/node)
#define NPB2    8     // nodes per block, layer-2 agg (32 lanes/node)
#define SCAN_B  256
#define SCAN_NB ((N_NODES + SCAN_B - 1) / SCAN_B)   // 196

typedef __bf16 bf16x8 __attribute__((ext_vector_type(8)));
typedef float  f32x4v __attribute__((ext_vector_type(4)));

// ---------------- workspace layout (element offsets, 4B units) ----------------
constexpr size_t pad64(size_t n){ return (n + 63) / 64 * 64; }
constexpr size_t O_CNT      = 0;
constexpr size_t O_ZERO_END = O_CNT      + pad64(N_NODES);
constexpr size_t O_RANK     = O_ZERO_END;
constexpr size_t O_ROWPTR   = O_RANK     + pad64(N_EDGES);
constexpr size_t O_STMP     = O_ROWPTR   + pad64(N_NODES+1);
constexpr size_t O_BSUM     = O_STMP     + pad64(N_NODES);
constexpr size_t O_BOFF     = O_BSUM     + pad64(SCAN_NB);
constexpr size_t O_EREC     = O_BOFF     + pad64(SCAN_NB);    // uint2 per edge {src|l2h, l0h|l1h}
constexpr size_t O_WEATT    = O_EREC     + pad64((size_t)N_EDGES*2);
constexpr size_t O_XHB      = O_WEATT    + 64;                       // bf16 [N][128]
constexpr size_t O_AS1      = O_XHB      + pad64((size_t)N_NODES*C1/2);
constexpr size_t O_AD1      = O_AS1      + pad64((size_t)N_NODES*2);
constexpr size_t O_H1B      = O_AD1      + pad64((size_t)N_NODES*2);   // bf16 [N][128]
constexpr size_t O_XH2B     = O_H1B      + pad64((size_t)N_NODES*C1/2); // bf16 [N][40]
constexpr size_t O_AS2      = O_XH2B     + pad64((size_t)N_NODES*OUT_C/2);
constexpr size_t O_AD2      = O_AS2      + pad64(N_NODES);

__device__ __forceinline__ float lrelu(float v){ return v >= 0.f ? v : NEG_SLOPE*v; }
__device__ __forceinline__ float bfl(unsigned u){ return __uint_as_float(u << 16); }
__device__ __forceinline__ float bfh(unsigned u){ return __uint_as_float(u & 0xFFFF0000u); }
__device__ __forceinline__ unsigned short f2bf(float f){
  unsigned u = __float_as_uint(f);
  return (unsigned short)((u + 0x7FFFu + ((u >> 16) & 1u)) >> 16);   // RNE
}
__device__ __forceinline__ unsigned f2h(float f){
  return (unsigned)__half_as_ushort(__float2half(f));
}
__device__ __forceinline__ float h2f(unsigned u){
  return __half2float(__ushort_as_half((unsigned short)(u & 0xFFFFu)));
}

// ---------------- K1: in-degree + per-edge rank (atomic return value is free) ----------------
__global__ void k_count(const int* __restrict__ dst, int* __restrict__ cnt,
                        int* __restrict__ rank){
  int e = blockIdx.x*blockDim.x + threadIdx.x;
  if (e >= N_EDGES) return;
  rank[e] = atomicAdd(&cnt[dst[e]], 1);
}

// ---------------- K2: device-wide exclusive scan, 3 wide dispatches ----------------
__global__ void __launch_bounds__(SCAN_B) k_scan1(const int* __restrict__ cnt,
                                                  int* __restrict__ stmp,
                                                  int* __restrict__ bsum){
  int blk = blockIdx.x, t = threadIdx.x;
  int i = blk*SCAN_B + t;
  int v = (i < N_NODES) ? cnt[i] : 0;
  int lane = t & 63, w = t >> 6;
  int x = v;
  #pragma unroll
  for (int off = 1; off < 64; off <<= 1){
    int y = __shfl_up(x, off);
    if (lane >= off) x += y;
  }
  __shared__ int wsum[SCAN_B/64];
  if (lane == 63) wsum[w] = x;
  __syncthreads();
  int add = 0;
  for (int k = 0; k < w; k++) add += wsum[k];
  x += add;
  if (i < N_NODES) stmp[i] = x;
  if (t == SCAN_B-1) bsum[blk] = x;
}

// scan2 + fused weatt (tiny attention-projection matrices) — saves a dispatch
__global__ void __launch_bounds__(SCAN_B) k_scan2(const int* __restrict__ bsum,
                                                  int* __restrict__ boff,
                                                  const float* __restrict__ We1,
                                                  const float* __restrict__ ae1,
                                                  const float* __restrict__ We2,
                                                  const float* __restrict__ ae2,
                                                  float* __restrict__ weatt){
  int t = threadIdx.x;
  int v = (t < SCAN_NB) ? bsum[t] : 0;
  int lane = t & 63, w = t >> 6;
  int x = v;
  #pragma unroll
  for (int off = 1; off < 64; off <<= 1){
    int y = __shfl_up(x, off);
    if (lane >= off) x += y;
  }
  __shared__ int wsum[SCAN_B/64];
  if (lane == 63) wsum[w] = x;
  __syncthreads();
  int add = 0;
  for (int k = 0; k < w; k++) add += wsum[k];
  x += add;                      // inclusive
  if (t < SCAN_NB) boff[t] = x - v;  // exclusive
  if (t < 10){
    int k = t >> 1, h = t & 1;
    float s = 0.f;
    for (int c = 0; c < HID; c++) s += We1[k*C1 + h*HID + c] * ae1[h*HID + c];
    weatt[k*2 + h] = s;
  } else if (t < 15){
    int k = t - 10;
    float s = 0.f;
    for (int c = 0; c < OUT_C; c++) s += We2[k*OUT_C + c] * ae2[c];
    weatt[10 + k] = s;
  }
}

__global__ void __launch_bounds__(SCAN_B) k_scan3(const int* __restrict__ stmp,
                                                  const int* __restrict__ boff,
                                                  int* __restrict__ rowptr){
  int blk = blockIdx.x, t = threadIdx.x;
  int i = blk*SCAN_B + t;
  if (i < N_NODES) rowptr[i+1] = stmp[i] + boff[blk];
  if (i == 0) rowptr[0] = 0;
}

// ---------------- K3: scatter edges into CSR, atomic-free, 8B packed records ----------------
__global__ void k_scatter(const int* __restrict__ src, const int* __restrict__ dst,
                          const int* __restrict__ rank,
                          const float* __restrict__ eattr, const int* __restrict__ rowptr,
                          const float* __restrict__ weatt,
                          uint2* __restrict__ erec){
  int e = blockIdx.x*blockDim.x + threadIdx.x;
  if (e >= N_EDGES) return;
  int d = dst[e];
  int pos = rowptr[d] + rank[e];
  float a[EDIM];
  #pragma unroll
  for (int k = 0; k < EDIM; k++) a[k] = eattr[e*EDIM + k];
  float l0 = 0.f, l1 = 0.f, l2 = 0.f;
  #pragma unroll
  for (int k = 0; k < EDIM; k++){
    l0 += a[k]*weatt[k*2 + 0];
    l1 += a[k]*weatt[k*2 + 1];
    l2 += a[k]*weatt[10 + k];
  }
  unsigned w0 = (unsigned)src[e] | (f2h(l2) << 16);
  unsigned w1 = f2h(l0) | (f2h(l1) << 16);
  erec[pos] = make_uint2(w0, w1);
}

// ---------------- K5: xh1 = x @ W1 via MFMA bf16 (fused att1, bf16 out) ----------------
// 64 rows/block, 4 waves x 16 rows; K=128 in 4 steps of 32; 8 col-tiles of 16.
// Operand k-mapping: elem e of lane-group g (=lane>>4) covers k = 8g+e for BOTH A and B
// (any consistent bijection is valid); C/D layout: col=lane&15, row=4*(lane>>4)+reg (HW-verified).
__global__ void __launch_bounds__(256) k_gemm1(const float* __restrict__ x,
                                               const float* __restrict__ W,
                                               const float* __restrict__ a_src,
                                               const float* __restrict__ a_dst,
                                               unsigned short* __restrict__ xhb,
                                               float* __restrict__ as_o,
                                               float* __restrict__ ad_o){
  __shared__ __align__(16) unsigned char smem[128*136*2];     // 34816 B
  __bf16 (*wt)[136] = (__bf16(*)[136])smem;                   // W^T bf16: wt[col][k]
  float  (*eps)[132] = (float(*)[132])smem;                   // epilogue f32 [64][132] (33792 B)
  int tid = threadIdx.x;
  int wv = tid >> 6, L = tid & 63;
  int g = L >> 4, c16 = L & 15;
  int r0 = blockIdx.x * 64;

  // stage W^T as bf16 (one-time per block)
  for (int i = tid; i < F_IN*C1; i += 256){
    int k = i >> 7, c = i & 127;
    wt[c][k] = (__bf16)W[i];
  }
  __syncthreads();

  f32x4v acc[8];
  #pragma unroll
  for (int ct = 0; ct < 8; ct++) acc[ct] = (f32x4v){0.f, 0.f, 0.f, 0.f};

  int arow = r0 + wv*16 + c16;
  bool aok = arow < N_NODES;
  const float* xrow = &x[(size_t)arow*F_IN];
  #pragma unroll
  for (int ks = 0; ks < 4; ks++){
    int k0 = ks*32 + g*8;
    bf16x8 a;
    if (aok){
      float4 v0 = *(const float4*)&xrow[k0];
      float4 v1 = *(const float4*)&xrow[k0 + 4];
      a[0]=(__bf16)v0.x; a[1]=(__bf16)v0.y; a[2]=(__bf16)v0.z; a[3]=(__bf16)v0.w;
      a[4]=(__bf16)v1.x; a[5]=(__bf16)v1.y; a[6]=(__bf16)v1.z; a[7]=(__bf16)v1.w;
    } else {
      a = (bf16x8)(__bf16)0.f;
    }
    #pragma unroll
    for (int ct = 0; ct < 8; ct++){
      bf16x8 b = *(const bf16x8*)&wt[ct*16 + c16][k0];
      acc[ct] = __builtin_amdgcn_mfma_f32_16x16x32_bf16(a, b, acc[ct], 0, 0, 0);
    }
  }
  __syncthreads();   // all wt reads done; reuse LDS as epilogue buffer

  #pragma unroll
  for (int ct = 0; ct < 8; ct++){
    #pragma unroll
    for (int r = 0; r < 4; r++)
      eps[wv*16 + g*4 + r][ct*16 + c16] = acc[ct][r];
  }
  __syncthreads();

  // readout: thread t -> row t>>2, 32-col block (t&3); coalesced bf16 store + fused att dots
  int row = tid >> 2, cb = tid & 3;
  int grow = r0 + row;
  float vals[32];
  #pragma unroll
  for (int j = 0; j < 32; j++) vals[j] = eps[row][cb*32 + j];
  if (grow < N_NODES){
    unsigned pk[16];
    #pragma unroll
    for (int j = 0; j < 16; j++)
      pk[j] = (unsigned)f2bf(vals[2*j]) | ((unsigned)f2bf(vals[2*j+1]) << 16);
    uint4* d4 = (uint4*)&xhb[(size_t)grow*C1 + cb*32];
    d4[0] = make_uint4(pk[0],pk[1],pk[2],pk[3]);
    d4[1] = make_uint4(pk[4],pk[5],pk[6],pk[7]);
    d4[2] = make_uint4(pk[8],pk[9],pk[10],pk[11]);
    d4[3] = make_uint4(pk[12],pk[13],pk[14],pk[15]);
  }
  float s = 0.f, d = 0.f;
  #pragma unroll
  for (int j = 0; j < 32; j++){
    s += vals[j]*a_src[cb*32 + j];
    d += vals[j]*a_dst[cb*32 + j];
  }
  s += __shfl_xor(s, 1);
  d += __shfl_xor(d, 1);
  if ((cb & 1) == 0 && grow < N_NODES){
    int h = cb >> 1;
    as_o[grow*2 + h] = s;
    ad_o[grow*2 + h] = d;
  }
}

// ---------------- K7: layer-1 aggregation; 16 lanes per node, no barriers; bf16 h1 out ----------------
__global__ void __launch_bounds__(256) k_agg1(const unsigned short* __restrict__ xhb,
    const int* __restrict__ rowptr, const uint2* __restrict__ erec,
    const float* __restrict__ as1, const float* __restrict__ ad1,
    const float* __restrict__ b1, unsigned short* __restrict__ h1b){
  __shared__ float2 eC[NPB1][CAPN+1];   // interleaved (e0,e1) — padded row kills bank conflicts
  __shared__ int    sC[NPB1][CAPN+1];
  int t = threadIdx.x;
  int g = t >> 4, l = t & 15;
  int n = blockIdx.x*NPB1 + g;
  if (n >= N_NODES) return;
  int beg = rowptr[n], end = rowptr[n+1];
  int deg = end - beg;
  float2 adn = *(const float2*)&ad1[n*2];
  bool cached = (deg <= CAPN);

  // phase A: exp(logit) -> LDS (group-local), sums via 4-step shuffle
  float s0 = 0.f, s1 = 0.f, la0 = 0.f, la1 = 0.f;
  for (int i = l; i < deg; i += 16){
    uint2 r = erec[(size_t)beg + i];
    int s = r.x & 0xFFFFu;
    float al0 = h2f(r.y), al1 = h2f(r.y >> 16);
    float2 a = *(const float2*)&as1[s*2];
    float e0 = expf(lrelu(a.x + adn.x + al0));
    float e1 = expf(lrelu(a.y + adn.y + al1));
    if (cached){ sC[g][i] = s * C1; eC[g][i] = make_float2(e0, e1); }
    s0 += e0; s1 += e1; la0 += al0; la1 += al1;
  }
  #pragma unroll
  for (int off = 1; off < 16; off <<= 1){
    s0 += __shfl_xor(s0, off); s1 += __shfl_xor(s1, off);
    la0 += __shfl_xor(la0, off); la1 += __shfl_xor(la1, off);
  }
  float inv = 1.f / fmaxf((float)deg, 1.f);
  float2 asn = *(const float2*)&as1[n*2];
  float sl0 = lrelu(asn.x + adn.x + la0*inv);
  float sl1 = lrelu(asn.y + adn.y + la1*inv);
  float es0 = expf(sl0), es1 = expf(sl1);
  float S0 = s0 + es0 + 1e-16f;
  float S1 = s1 + es1 + 1e-16f;

  // phase B: per edge — e broadcast from LDS, 16 lanes x 16B coalesced row
  int head = l >> 3;                   // lane 0..7 head0 (cols 0..63), 8..15 head1
  float acc[8];
  #pragma unroll
  for (int j = 0; j < 8; j++) acc[j] = 0.f;
  if (cached){
    for (int k = 0; k < deg; k++){
      float2 e2 = eC[g][k];
      float e = head ? e2.y : e2.x;
      uint4 r = *(const uint4*)&xhb[sC[g][k] + l*8];
      acc[0] += e*bfl(r.x); acc[1] += e*bfh(r.x);
      acc[2] += e*bfl(r.y); acc[3] += e*bfh(r.y);
      acc[4] += e*bfl(r.z); acc[5] += e*bfh(r.z);
      acc[6] += e*bfl(r.w); acc[7] += e*bfh(r.w);
    }
  } else {
    // fallback (deg > CAPN): recompute e per edge, group-local, ~never taken
    for (int k = 0; k < deg; k++){
      uint2 rr = erec[(size_t)beg + k];
      int s = rr.x & 0xFFFFu;
      float2 a = *(const float2*)&as1[s*2];
      float e = head ? expf(lrelu(a.y + adn.y + h2f(rr.y >> 16)))
                     : expf(lrelu(a.x + adn.x + h2f(rr.y)));
      uint4 r = *(const uint4*)&xhb[(size_t)s*C1 + l*8];
      acc[0] += e*bfl(r.x); acc[1] += e*bfh(r.x);
      acc[2] += e*bfl(r.y); acc[3] += e*bfh(r.y);
      acc[4] += e*bfl(r.z); acc[5] += e*bfh(r.z);
      acc[6] += e*bfl(r.w); acc[7] += e*bfh(r.w);
    }
  }
  // epilogue: each lane owns its 8 cols — pack to bf16, single 16B store
  float es = head ? es1 : es0;
  float den = head ? S1 : S0;
  uint4 r = *(const uint4*)&xhb[(size_t)n*C1 + l*8];
  float xs8[8];
  xs8[0]=bfl(r.x); xs8[1]=bfh(r.x); xs8[2]=bfl(r.y); xs8[3]=bfh(r.y);
  xs8[4]=bfl(r.z); xs8[5]=bfh(r.z); xs8[6]=bfl(r.w); xs8[7]=bfh(r.w);
  unsigned pk[4];
  #pragma unroll
  for (int p = 0; p < 4; p++){
    float v0 = (acc[2*p]   + es*xs8[2*p])   / den + b1[l*8 + 2*p];
    float v1 = (acc[2*p+1] + es*xs8[2*p+1]) / den + b1[l*8 + 2*p+1];
    v0 = v0 > 0.f ? v0 : expm1f(v0);   // ELU
    v1 = v1 > 0.f ? v1 : expm1f(v1);
    pk[p] = (unsigned)f2bf(v0) | ((unsigned)f2bf(v1) << 16);
  }
  *(uint4*)&h1b[(size_t)n*C1 + l*8] = make_uint4(pk[0], pk[1], pk[2], pk[3]);
}

// ---------------- K8: xh2 = h1 @ W2 via MFMA bf16 (fused att2, bf16 out) ----------------
// 64 rows/block, 4 waves x 16 rows; K=128 in 4 steps; 3 col-tiles (40 cols padded to 48).
__global__ void __launch_bounds__(256) k_gemm2(const unsigned short* __restrict__ h1b,
    const float* __restrict__ W2, const float* __restrict__ a_src2,
    const float* __restrict__ a_dst2,
    unsigned short* __restrict__ xh2b, float* __restrict__ as_o, float* __restrict__ ad_o){
  __shared__ __align__(16) unsigned char smem[64*52*4];        // 13312 B
  __bf16 (*wt)[136] = (__bf16(*)[136])smem;                    // W2^T bf16 [48][136] = 13056 B
  float  (*eps)[52] = (float(*)[52])smem;                      // epilogue f32 [64][52]
  int tid = threadIdx.x;
  int wv = tid >> 6, L = tid & 63;
  int g = L >> 4, c16 = L & 15;
  int r0 = blockIdx.x * 64;

  // stage W2^T bf16, pad cols 40..47 with zero
  for (int i = tid; i < 48*F_IN; i += 256){
    int c = i >> 7, k = i & 127;
    wt[c][k] = (c < OUT_C) ? (__bf16)W2[k*OUT_C + c] : (__bf16)0.f;
  }
  __syncthreads();

  f32x4v acc[3];
  #pragma unroll
  for (int ct = 0; ct < 3; ct++) acc[ct] = (f32x4v){0.f, 0.f, 0.f, 0.f};

  int arow = r0 + wv*16 + c16;
  bool aok = arow < N_NODES;
  const unsigned short* hrow = &h1b[(size_t)arow*C1];
  #pragma unroll
  for (int ks = 0; ks < 4; ks++){
    int k0 = ks*32 + g*8;
    bf16x8 a;
    if (aok) a = *(const bf16x8*)&hrow[k0];
    else     a = (bf16x8)(__bf16)0.f;
    #pragma unroll
    for (int ct = 0; ct < 3; ct++){
      bf16x8 b = *(const bf16x8*)&wt[ct*16 + c16][k0];
      acc[ct] = __builtin_amdgcn_mfma_f32_16x16x32_bf16(a, b, acc[ct], 0, 0, 0);
    }
  }
  __syncthreads();

  #pragma unroll
  for (int ct = 0; ct < 3; ct++){
    #pragma unroll
    for (int r = 0; r < 4; r++)
      eps[wv*16 + g*4 + r][ct*16 + c16] = acc[ct][r];
  }
  __syncthreads();

  // readout: thread t -> row t>>2, 12-col block (t&3); bf16 stores + fused att2 dots
  int row = tid >> 2, cb = tid & 3;
  int grow = r0 + row;
  int base = cb*12;
  float vals[12];
  #pragma unroll
  for (int j = 0; j < 12; j++) vals[j] = eps[row][base + j];
  int npair = (cb < 3) ? 6 : 2;        // cb=3 covers cols 36..47; only 36..39 valid
  if (grow < N_NODES){
    unsigned* dp = (unsigned*)&xh2b[(size_t)grow*OUT_C + base];
    for (int jj = 0; jj < npair; jj++)
      dp[jj] = (unsigned)f2bf(vals[2*jj]) | ((unsigned)f2bf(vals[2*jj+1]) << 16);
  }
  float s = 0.f, d = 0.f;
  #pragma unroll
  for (int j = 0; j < 12; j++){
    int col = base + j;
    if (col < OUT_C){
      s += vals[j]*a_src2[col];
      d += vals[j]*a_dst2[col];
    }
  }
  s += __shfl_xor(s, 1); s += __shfl_xor(s, 2);
  d += __shfl_xor(d, 1); d += __shfl_xor(d, 2);
  if (cb == 0 && grow < N_NODES){
    as_o[grow] = s;
    ad_o[grow] = d;
  }
}

// ---------------- K10: layer-2 aggregation + log_softmax; 32 lanes per node ----------------
__global__ void __launch_bounds__(256) k_agg2(const unsigned short* __restrict__ xh2b,
    const int* __restrict__ rowptr, const uint2* __restrict__ erec,
    const float* __restrict__ as2, const float* __restrict__ ad2,
    const float* __restrict__ b2, float* __restrict__ out){
  __shared__ float eC[NPB2][CAPN+1];
  __shared__ int   sC[NPB2][CAPN+1];
  int t = threadIdx.x;
  int g = t >> 5, l = t & 31;
  int n = blockIdx.x*NPB2 + g;
  if (n >= N_NODES) return;
  int beg = rowptr[n], end = rowptr[n+1];
  int deg = end - beg;
  float adv = ad2[n];
  bool cached = (deg <= CAPN);

  // phase A
  float ss = 0.f, la = 0.f;
  for (int i = l; i < deg; i += 32){
    uint2 r = erec[(size_t)beg + i];
    int s = r.x & 0xFFFFu;
    float al2 = h2f(r.x >> 16);
    float e = expf(lrelu(as2[s] + adv + al2));
    if (cached){ sC[g][i] = s * OUT_C; eC[g][i] = e; }
    ss += e; la += al2;
  }
  #pragma unroll
  for (int off = 1; off < 32; off <<= 1){
    ss += __shfl_xor(ss, off);
    la += __shfl_xor(la, off);
  }
  float inv = 1.f / fmaxf((float)deg, 1.f);
  float sl = lrelu(as2[n] + adv + la*inv);
  float es = expf(sl);
  float S = ss + es + 1e-16f;

  // phase B: lanes 0..19 own cols {2l, 2l+1}
  float a0 = 0.f, a1 = 0.f;
  if (l < 20){
    if (cached){
      for (int k = 0; k < deg; k++){
        float e = eC[g][k];
        unsigned u = *(const unsigned*)&xh2b[sC[g][k] + l*2];
        a0 += e*bfl(u); a1 += e*bfh(u);
      }
    } else {
      for (int k = 0; k < deg; k++){
        uint2 rr = erec[(size_t)beg + k];
        int s = rr.x & 0xFFFFu;
        float e = expf(lrelu(as2[s] + adv + h2f(rr.x >> 16)));
        unsigned u = *(const unsigned*)&xh2b[(size_t)s*OUT_C + l*2];
        a0 += e*bfl(u); a1 += e*bfh(u);
      }
    }
  }
  float o0 = -INFINITY, o1 = -INFINITY;
  if (l < 20){
    unsigned u = *(const unsigned*)&xh2b[(size_t)n*OUT_C + l*2];
    o0 = (a0 + es*bfl(u)) / S + b2[l*2 + 0];
    o1 = (a1 + es*bfh(u)) / S + b2[l*2 + 1];
  }
  // log_softmax over 40 cols (2 per lane in lanes 0..19)
  float mm = fmaxf(o0, o1);
  #pragma unroll
  for (int off = 1; off < 32; off <<= 1) mm = fmaxf(mm, __shfl_xor(mm, off));
  float e = (l < 20) ? (expf(o0 - mm) + expf(o1 - mm)) : 0.f;
  #pragma unroll
  for (int off = 1; off < 32; off <<= 1) e += __shfl_xor(e, off);
  if (l < 20){
    float lse = logf(e);
    out[(size_t)n*OUT_C + l*2 + 0] = o0 - mm - lse;
    out[(size_t)n*OUT_C + l*2 + 1] = o1 - mm - lse;
  }
}

// ---------------- host launcher ----------------
extern "C" void kernel_launch(void* const* d_in, const int* in_sizes, int n_in,
                              void* d_out, int out_size, void* d_ws, size_t ws_size,
                              hipStream_t stream){
  const float* x        = (const float*)d_in[0];
  const int*   ei       = (const int*)  d_in[1];
  const float* eattr    = (const float*)d_in[2];
  const float* W1       = (const float*)d_in[3];
  const float* att_src1 = (const float*)d_in[4];
  const float* att_dst1 = (const float*)d_in[5];
  const float* We1      = (const float*)d_in[6];
  const float* att_e1   = (const float*)d_in[7];
  const float* b1       = (const float*)d_in[8];
  const float* W2       = (const float*)d_in[9];
  const float* att_src2 = (const float*)d_in[10];
  const float* att_dst2 = (const float*)d_in[11];
  const float* We2      = (const float*)d_in[12];
  const float* att_e2   = (const float*)d_in[13];
  const float* b2       = (const float*)d_in[14];
  const int* src = ei;
  const int* dst = ei + N_EDGES;

  float* wsf    = (float*)d_ws;
  int*   cnt     = (int*)(wsf + O_CNT);
  int*   rank    = (int*)(wsf + O_RANK);
  int*   rowptr  = (int*)(wsf + O_ROWPTR);
  int*   stmp    = (int*)(wsf + O_STMP);
  int*   bsum    = (int*)(wsf + O_BSUM);
  int*   boff    = (int*)(wsf + O_BOFF);
  uint2* erec    = (uint2*)(wsf + O_EREC);
  float* weatt   = wsf + O_WEATT;
  unsigned short* xhb  = (unsigned short*)(wsf + O_XHB);
  float* as1     = wsf + O_AS1;
  float* ad1     = wsf + O_AD1;
  unsigned short* h1b  = (unsigned short*)(wsf + O_H1B);
  unsigned short* xh2b = (unsigned short*)(wsf + O_XH2B);
  float* as2     = wsf + O_AS2;
  float* ad2     = wsf + O_AD2;
  float* out     = (float*)d_out;

  hipMemsetAsync(wsf + O_CNT, 0, O_ZERO_END*sizeof(float), stream);

  const int EB = (N_EDGES + 255) / 256;

  k_count  <<<EB, 256, 0, stream>>>(dst, cnt, rank);
  k_scan1  <<<SCAN_NB, SCAN_B, 0, stream>>>(cnt, stmp, bsum);
  k_scan2  <<<1, SCAN_B, 0, stream>>>(bsum, boff, We1, att_e1, We2, att_e2, weatt);
  k_scan3  <<<SCAN_NB, SCAN_B, 0, stream>>>(stmp, boff, rowptr);
  k_scatter<<<EB, 256, 0, stream>>>(src, dst, rank, eattr, rowptr, weatt, erec);

  k_gemm1  <<<(N_NODES + 63)/64, 256, 0, stream>>>(x, W1, att_src1, att_dst1, xhb, as1, ad1);
  k_agg1   <<<(N_NODES + NPB1 - 1)/NPB1, 256, 0, stream>>>(xhb, rowptr, erec, as1, ad1, b1, h1b);

  k_gemm2  <<<(N_NODES + 63)/64, 256, 0, stream>>>(h1b, W2, att_src2, att_dst2, xh2b, as2, ad2);
  k_agg2   <<<(N_NODES + NPB2 - 1)/NPB2, 256, 0, stream>>>(xh2b, rowptr, erec, as2, ad2, b2, out);
}

// Round 13
// 167.152 us; speedup vs baseline: 1.1490x; 1.0034x over previous
//
#include <hip/hip_runtime.h>
#include <hip/hip_fp16.h>
#include <math.h>

#define N_NODES 50000
#define N_EDGES 800000
#define F_IN    128
#define HID     64
#define HEADS   2
#define C1      128   // HEADS*HID
#define OUT_C   40
#define EDIM    5
#define NEG_SLOPE 0.2f
#define CAPN    64    // per-node LDS edge cache (Poisson(16): P(deg>64)~1e-20; fallback kept)
#define NPB1    16    // nodes per block, layer-1 agg (16 lanes/node)
#define NPB2    8     // nodes per block, layer-2 agg (32 lanes/node)
#define SCAN_B  256
#define SCAN_NB ((N_NODES + SCAN_B - 1) / SCAN_B)   // 196

typedef __bf16 bf16x8 __attribute__((ext_vector_type(8)));
typedef float  f32x4v __attribute__((ext_vector_type(4)));

// ---------------- workspace layout (element offsets, 4B units) ----------------
constexpr size_t pad64(size_t n){ return (n + 63) / 64 * 64; }
constexpr size_t O_CNT      = 0;
constexpr size_t O_ZERO_END = O_CNT      + pad64(N_NODES);
constexpr size_t O_RANK     = O_ZERO_END;
constexpr size_t O_ROWPTR   = O_RANK     + pad64(N_EDGES);
constexpr size_t O_STMP     = O_ROWPTR   + pad64(N_NODES+1);
constexpr size_t O_BSUM     = O_STMP     + pad64(N_NODES);
constexpr size_t O_BOFF     = O_BSUM     + pad64(SCAN_NB);
constexpr size_t O_EREC     = O_BOFF     + pad64(SCAN_NB);    // uint2 per edge {src|l2h, l0h|l1h}
constexpr size_t O_WEATT    = O_EREC     + pad64((size_t)N_EDGES*2);
constexpr size_t O_XHB      = O_WEATT    + 64;                       // bf16 [N][128]
constexpr size_t O_AS1      = O_XHB      + pad64((size_t)N_NODES*C1/2);
constexpr size_t O_AD1      = O_AS1      + pad64((size_t)N_NODES*2);
constexpr size_t O_H1B      = O_AD1      + pad64((size_t)N_NODES*2);   // bf16 [N][128]
constexpr size_t O_XH2B     = O_H1B      + pad64((size_t)N_NODES*C1/2); // bf16 [N][40]
constexpr size_t O_AS2      = O_XH2B     + pad64((size_t)N_NODES*OUT_C/2);
constexpr size_t O_AD2      = O_AS2      + pad64(N_NODES);

__device__ __forceinline__ float lrelu(float v){ return v >= 0.f ? v : NEG_SLOPE*v; }
__device__ __forceinline__ float bfl(unsigned u){ return __uint_as_float(u << 16); }
__device__ __forceinline__ float bfh(unsigned u){ return __uint_as_float(u & 0xFFFF0000u); }
__device__ __forceinline__ unsigned short f2bf(float f){
  unsigned u = __float_as_uint(f);
  return (unsigned short)((u + 0x7FFFu + ((u >> 16) & 1u)) >> 16);   // RNE
}
__device__ __forceinline__ unsigned f2h(float f){
  return (unsigned)__half_as_ushort(__float2half(f));
}
__device__ __forceinline__ float h2f(unsigned u){
  return __half2float(__ushort_as_half((unsigned short)(u & 0xFFFFu)));
}

// ---------------- K0: zero the cnt array (rocclr fillBuffer is ~41us for this; we do ~2us) ----
__global__ void k_zero(int* __restrict__ p, int n){
  int i = blockIdx.x*blockDim.x + threadIdx.x;
  if (i < n) p[i] = 0;
}

// ---------------- K1: in-degree + per-edge rank (atomic return value is free) ----------------
__global__ void k_count(const int* __restrict__ dst, int* __restrict__ cnt,
                        int* __restrict__ rank){
  int e = blockIdx.x*blockDim.x + threadIdx.x;
  if (e >= N_EDGES) return;
  rank[e] = atomicAdd(&cnt[dst[e]], 1);
}

// ---------------- K2: device-wide exclusive scan, 3 wide dispatches ----------------
__global__ void __launch_bounds__(SCAN_B) k_scan1(const int* __restrict__ cnt,
                                                  int* __restrict__ stmp,
                                                  int* __restrict__ bsum){
  int blk = blockIdx.x, t = threadIdx.x;
  int i = blk*SCAN_B + t;
  int v = (i < N_NODES) ? cnt[i] : 0;
  int lane = t & 63, w = t >> 6;
  int x = v;
  #pragma unroll
  for (int off = 1; off < 64; off <<= 1){
    int y = __shfl_up(x, off);
    if (lane >= off) x += y;
  }
  __shared__ int wsum[SCAN_B/64];
  if (lane == 63) wsum[w] = x;
  __syncthreads();
  int add = 0;
  for (int k = 0; k < w; k++) add += wsum[k];
  x += add;
  if (i < N_NODES) stmp[i] = x;
  if (t == SCAN_B-1) bsum[blk] = x;
}

// scan2 + fused weatt (tiny attention-projection matrices) — saves a dispatch
__global__ void __launch_bounds__(SCAN_B) k_scan2(const int* __restrict__ bsum,
                                                  int* __restrict__ boff,
                                                  const float* __restrict__ We1,
                                                  const float* __restrict__ ae1,
                                                  const float* __restrict__ We2,
                                                  const float* __restrict__ ae2,
                                                  float* __restrict__ weatt){
  int t = threadIdx.x;
  int v = (t < SCAN_NB) ? bsum[t] : 0;
  int lane = t & 63, w = t >> 6;
  int x = v;
  #pragma unroll
  for (int off = 1; off < 64; off <<= 1){
    int y = __shfl_up(x, off);
    if (lane >= off) x += y;
  }
  __shared__ int wsum[SCAN_B/64];
  if (lane == 63) wsum[w] = x;
  __syncthreads();
  int add = 0;
  for (int k = 0; k < w; k++) add += wsum[k];
  x += add;                      // inclusive
  if (t < SCAN_NB) boff[t] = x - v;  // exclusive
  if (t < 10){
    int k = t >> 1, h = t & 1;
    float s = 0.f;
    for (int c = 0; c < HID; c++) s += We1[k*C1 + h*HID + c] * ae1[h*HID + c];
    weatt[k*2 + h] = s;
  } else if (t < 15){
    int k = t - 10;
    float s = 0.f;
    for (int c = 0; c < OUT_C; c++) s += We2[k*OUT_C + c] * ae2[c];
    weatt[10 + k] = s;
  }
}

__global__ void __launch_bounds__(SCAN_B) k_scan3(const int* __restrict__ stmp,
                                                  const int* __restrict__ boff,
                                                  int* __restrict__ rowptr){
  int blk = blockIdx.x, t = threadIdx.x;
  int i = blk*SCAN_B + t;
  if (i < N_NODES) rowptr[i+1] = stmp[i] + boff[blk];
  if (i == 0) rowptr[0] = 0;
}

// ---------------- K3: scatter edges into CSR, atomic-free, 8B packed records ----------------
__global__ void k_scatter(const int* __restrict__ src, const int* __restrict__ dst,
                          const int* __restrict__ rank,
                          const float* __restrict__ eattr, const int* __restrict__ rowptr,
                          const float* __restrict__ weatt,
                          uint2* __restrict__ erec){
  int e = blockIdx.x*blockDim.x + threadIdx.x;
  if (e >= N_EDGES) return;
  int d = dst[e];
  int pos = rowptr[d] + rank[e];
  float a[EDIM];
  #pragma unroll
  for (int k = 0; k < EDIM; k++) a[k] = eattr[e*EDIM + k];
  float l0 = 0.f, l1 = 0.f, l2 = 0.f;
  #pragma unroll
  for (int k = 0; k < EDIM; k++){
    l0 += a[k]*weatt[k*2 + 0];
    l1 += a[k]*weatt[k*2 + 1];
    l2 += a[k]*weatt[10 + k];
  }
  unsigned w0 = (unsigned)src[e] | (f2h(l2) << 16);
  unsigned w1 = f2h(l0) | (f2h(l1) << 16);
  erec[pos] = make_uint2(w0, w1);
}

// ---------------- K5: xh1 = x @ W1 via MFMA bf16 (fused att1, bf16 out) ----------------
// 64 rows/block, 4 waves x 16 rows; K=128 in 4 steps of 32; 8 col-tiles of 16.
// Operand k-mapping: elem e of lane-group g (=lane>>4) covers k = 8g+e for BOTH A and B
// (any consistent bijection is valid); C/D layout: col=lane&15, row=4*(lane>>4)+reg (HW-verified).
__global__ void __launch_bounds__(256) k_gemm1(const float* __restrict__ x,
                                               const float* __restrict__ W,
                                               const float* __restrict__ a_src,
                                               const float* __restrict__ a_dst,
                                               unsigned short* __restrict__ xhb,
                                               float* __restrict__ as_o,
                                               float* __restrict__ ad_o){
  __shared__ __align__(16) unsigned char smem[128*136*2];     // 34816 B
  __bf16 (*wt)[136] = (__bf16(*)[136])smem;                   // W^T bf16: wt[col][k]
  float  (*eps)[132] = (float(*)[132])smem;                   // epilogue f32 [64][132] (33792 B)
  int tid = threadIdx.x;
  int wv = tid >> 6, L = tid & 63;
  int g = L >> 4, c16 = L & 15;
  int r0 = blockIdx.x * 64;

  // stage W^T as bf16 (one-time per block)
  for (int i = tid; i < F_IN*C1; i += 256){
    int k = i >> 7, c = i & 127;
    wt[c][k] = (__bf16)W[i];
  }
  __syncthreads();

  f32x4v acc[8];
  #pragma unroll
  for (int ct = 0; ct < 8; ct++) acc[ct] = (f32x4v){0.f, 0.f, 0.f, 0.f};

  int arow = r0 + wv*16 + c16;
  bool aok = arow < N_NODES;
  const float* xrow = &x[(size_t)arow*F_IN];
  #pragma unroll
  for (int ks = 0; ks < 4; ks++){
    int k0 = ks*32 + g*8;
    bf16x8 a;
    if (aok){
      float4 v0 = *(const float4*)&xrow[k0];
      float4 v1 = *(const float4*)&xrow[k0 + 4];
      a[0]=(__bf16)v0.x; a[1]=(__bf16)v0.y; a[2]=(__bf16)v0.z; a[3]=(__bf16)v0.w;
      a[4]=(__bf16)v1.x; a[5]=(__bf16)v1.y; a[6]=(__bf16)v1.z; a[7]=(__bf16)v1.w;
    } else {
      a = (bf16x8)(__bf16)0.f;
    }
    #pragma unroll
    for (int ct = 0; ct < 8; ct++){
      bf16x8 b = *(const bf16x8*)&wt[ct*16 + c16][k0];
      acc[ct] = __builtin_amdgcn_mfma_f32_16x16x32_bf16(a, b, acc[ct], 0, 0, 0);
    }
  }
  __syncthreads();   // all wt reads done; reuse LDS as epilogue buffer

  #pragma unroll
  for (int ct = 0; ct < 8; ct++){
    #pragma unroll
    for (int r = 0; r < 4; r++)
      eps[wv*16 + g*4 + r][ct*16 + c16] = acc[ct][r];
  }
  __syncthreads();

  // readout: thread t -> row t>>2, 32-col block (t&3); coalesced bf16 store + fused att dots
  int row = tid >> 2, cb = tid & 3;
  int grow = r0 + row;
  float vals[32];
  #pragma unroll
  for (int j = 0; j < 32; j++) vals[j] = eps[row][cb*32 + j];
  if (grow < N_NODES){
    unsigned pk[16];
    #pragma unroll
    for (int j = 0; j < 16; j++)
      pk[j] = (unsigned)f2bf(vals[2*j]) | ((unsigned)f2bf(vals[2*j+1]) << 16);
    uint4* d4 = (uint4*)&xhb[(size_t)grow*C1 + cb*32];
    d4[0] = make_uint4(pk[0],pk[1],pk[2],pk[3]);
    d4[1] = make_uint4(pk[4],pk[5],pk[6],pk[7]);
    d4[2] = make_uint4(pk[8],pk[9],pk[10],pk[11]);
    d4[3] = make_uint4(pk[12],pk[13],pk[14],pk[15]);
  }
  float s = 0.f, d = 0.f;
  #pragma unroll
  for (int j = 0; j < 32; j++){
    s += vals[j]*a_src[cb*32 + j];
    d += vals[j]*a_dst[cb*32 + j];
  }
  s += __shfl_xor(s, 1);
  d += __shfl_xor(d, 1);
  if ((cb & 1) == 0 && grow < N_NODES){
    int h = cb >> 1;
    as_o[grow*2 + h] = s;
    ad_o[grow*2 + h] = d;
  }
}

// ---------------- K7: layer-1 aggregation; 16 lanes per node, no barriers; bf16 h1 out ----------------
__global__ void __launch_bounds__(256) k_agg1(const unsigned short* __restrict__ xhb,
    const int* __restrict__ rowptr, const uint2* __restrict__ erec,
    const float* __restrict__ as1, const float* __restrict__ ad1,
    const float* __restrict__ b1, unsigned short* __restrict__ h1b){
  __shared__ float2 eC[NPB1][CAPN+1];   // interleaved (e0,e1) — padded row kills bank conflicts
  __shared__ int    sC[NPB1][CAPN+1];
  int t = threadIdx.x;
  int g = t >> 4, l = t & 15;
  int n = blockIdx.x*NPB1 + g;
  if (n >= N_NODES) return;
  int beg = rowptr[n], end = rowptr[n+1];
  int deg = end - beg;
  float2 adn = *(const float2*)&ad1[n*2];
  bool cached = (deg <= CAPN);

  // phase A: exp(logit) -> LDS (group-local), sums via 4-step shuffle
  float s0 = 0.f, s1 = 0.f, la0 = 0.f, la1 = 0.f;
  for (int i = l; i < deg; i += 16){
    uint2 r = erec[(size_t)beg + i];
    int s = r.x & 0xFFFFu;
    float al0 = h2f(r.y), al1 = h2f(r.y >> 16);
    float2 a = *(const float2*)&as1[s*2];
    float e0 = expf(lrelu(a.x + adn.x + al0));
    float e1 = expf(lrelu(a.y + adn.y + al1));
    if (cached){ sC[g][i] = s * C1; eC[g][i] = make_float2(e0, e1); }
    s0 += e0; s1 += e1; la0 += al0; la1 += al1;
  }
  #pragma unroll
  for (int off = 1; off < 16; off <<= 1){
    s0 += __shfl_xor(s0, off); s1 += __shfl_xor(s1, off);
    la0 += __shfl_xor(la0, off); la1 += __shfl_xor(la1, off);
  }
  float inv = 1.f / fmaxf((float)deg, 1.f);
  float2 asn = *(const float2*)&as1[n*2];
  float sl0 = lrelu(asn.x + adn.x + la0*inv);
  float sl1 = lrelu(asn.y + adn.y + la1*inv);
  float es0 = expf(sl0), es1 = expf(sl1);
  float S0 = s0 + es0 + 1e-16f;
  float S1 = s1 + es1 + 1e-16f;

  // phase B: per edge — e broadcast from LDS, 16 lanes x 16B coalesced row
  int head = l >> 3;                   // lane 0..7 head0 (cols 0..63), 8..15 head1
  float acc[8];
  #pragma unroll
  for (int j = 0; j < 8; j++) acc[j] = 0.f;
  if (cached){
    for (int k = 0; k < deg; k++){
      float2 e2 = eC[g][k];
      float e = head ? e2.y : e2.x;
      uint4 r = *(const uint4*)&xhb[sC[g][k] + l*8];
      acc[0] += e*bfl(r.x); acc[1] += e*bfh(r.x);
      acc[2] += e*bfl(r.y); acc[3] += e*bfh(r.y);
      acc[4] += e*bfl(r.z); acc[5] += e*bfh(r.z);
      acc[6] += e*bfl(r.w); acc[7] += e*bfh(r.w);
    }
  } else {
    // fallback (deg > CAPN): recompute e per edge, group-local, ~never taken
    for (int k = 0; k < deg; k++){
      uint2 rr = erec[(size_t)beg + k];
      int s = rr.x & 0xFFFFu;
      float2 a = *(const float2*)&as1[s*2];
      float e = head ? expf(lrelu(a.y + adn.y + h2f(rr.y >> 16)))
                     : expf(lrelu(a.x + adn.x + h2f(rr.y)));
      uint4 r = *(const uint4*)&xhb[(size_t)s*C1 + l*8];
      acc[0] += e*bfl(r.x); acc[1] += e*bfh(r.x);
      acc[2] += e*bfl(r.y); acc[3] += e*bfh(r.y);
      acc[4] += e*bfl(r.z); acc[5] += e*bfh(r.z);
      acc[6] += e*bfl(r.w); acc[7] += e*bfh(r.w);
    }
  }
  // epilogue: each lane owns its 8 cols — pack to bf16, single 16B store
  float es = head ? es1 : es0;
  float den = head ? S1 : S0;
  uint4 r = *(const uint4*)&xhb[(size_t)n*C1 + l*8];
  float xs8[8];
  xs8[0]=bfl(r.x); xs8[1]=bfh(r.x); xs8[2]=bfl(r.y); xs8[3]=bfh(r.y);
  xs8[4]=bfl(r.z); xs8[5]=bfh(r.z); xs8[6]=bfl(r.w); xs8[7]=bfh(r.w);
  unsigned pk[4];
  #pragma unroll
  for (int p = 0; p < 4; p++){
    float v0 = (acc[2*p]   + es*xs8[2*p])   / den + b1[l*8 + 2*p];
    float v1 = (acc[2*p+1] + es*xs8[2*p+1]) / den + b1[l*8 + 2*p+1];
    v0 = v0 > 0.f ? v0 : expm1f(v0);   // ELU
    v1 = v1 > 0.f ? v1 : expm1f(v1);
    pk[p] = (unsigned)f2bf(v0) | ((unsigned)f2bf(v1) << 16);
  }
  *(uint4*)&h1b[(size_t)n*C1 + l*8] = make_uint4(pk[0], pk[1], pk[2], pk[3]);
}

// ---------------- K8: xh2 = h1 @ W2 via MFMA bf16 (fused att2, bf16 out) ----------------
// 64 rows/block, 4 waves x 16 rows; K=128 in 4 steps; 3 col-tiles (40 cols padded to 48).
__global__ void __launch_bounds__(256) k_gemm2(const unsigned short* __restrict__ h1b,
    const float* __restrict__ W2, const float* __restrict__ a_src2,
    const float* __restrict__ a_dst2,
    unsigned short* __restrict__ xh2b, float* __restrict__ as_o, float* __restrict__ ad_o){
  __shared__ __align__(16) unsigned char smem[64*52*4];        // 13312 B
  __bf16 (*wt)[136] = (__bf16(*)[136])smem;                    // W2^T bf16 [48][136] = 13056 B
  float  (*eps)[52] = (float(*)[52])smem;                      // epilogue f32 [64][52]
  int tid = threadIdx.x;
  int wv = tid >> 6, L = tid & 63;
  int g = L >> 4, c16 = L & 15;
  int r0 = blockIdx.x * 64;

  // stage W2^T bf16, pad cols 40..47 with zero
  for (int i = tid; i < 48*F_IN; i += 256){
    int c = i >> 7, k = i & 127;
    wt[c][k] = (c < OUT_C) ? (__bf16)W2[k*OUT_C + c] : (__bf16)0.f;
  }
  __syncthreads();

  f32x4v acc[3];
  #pragma unroll
  for (int ct = 0; ct < 3; ct++) acc[ct] = (f32x4v){0.f, 0.f, 0.f, 0.f};

  int arow = r0 + wv*16 + c16;
  bool aok = arow < N_NODES;
  const unsigned short* hrow = &h1b[(size_t)arow*C1];
  #pragma unroll
  for (int ks = 0; ks < 4; ks++){
    int k0 = ks*32 + g*8;
    bf16x8 a;
    if (aok) a = *(const bf16x8*)&hrow[k0];
    else     a = (bf16x8)(__bf16)0.f;
    #pragma unroll
    for (int ct = 0; ct < 3; ct++){
      bf16x8 b = *(const bf16x8*)&wt[ct*16 + c16][k0];
      acc[ct] = __builtin_amdgcn_mfma_f32_16x16x32_bf16(a, b, acc[ct], 0, 0, 0);
    }
  }
  __syncthreads();

  #pragma unroll
  for (int ct = 0; ct < 3; ct++){
    #pragma unroll
    for (int r = 0; r < 4; r++)
      eps[wv*16 + g*4 + r][ct*16 + c16] = acc[ct][r];
  }
  __syncthreads();

  // readout: thread t -> row t>>2, 12-col block (t&3); bf16 stores + fused att2 dots
  int row = tid >> 2, cb = tid & 3;
  int grow = r0 + row;
  int base = cb*12;
  float vals[12];
  #pragma unroll
  for (int j = 0; j < 12; j++) vals[j] = eps[row][base + j];
  int npair = (cb < 3) ? 6 : 2;        // cb=3 covers cols 36..47; only 36..39 valid
  if (grow < N_NODES){
    unsigned* dp = (unsigned*)&xh2b[(size_t)grow*OUT_C + base];
    for (int jj = 0; jj < npair; jj++)
      dp[jj] = (unsigned)f2bf(vals[2*jj]) | ((unsigned)f2bf(vals[2*jj+1]) << 16);
  }
  float s = 0.f, d = 0.f;
  #pragma unroll
  for (int j = 0; j < 12; j++){
    int col = base + j;
    if (col < OUT_C){
      s += vals[j]*a_src2[col];
      d += vals[j]*a_dst2[col];
    }
  }
  s += __shfl_xor(s, 1); s += __shfl_xor(s, 2);
  d += __shfl_xor(d, 1); d += __shfl_xor(d, 2);
  if (cb == 0 && grow < N_NODES){
    as_o[grow] = s;
    ad_o[grow] = d;
  }
}

// ---------------- K10: layer-2 aggregation + log_softmax; 32 lanes per node ----------------
__global__ void __launch_bounds__(256) k_agg2(const unsigned short* __restrict__ xh2b,
    const int* __restrict__ rowptr, const uint2* __restrict__ erec,
    const float* __restrict__ as2, const float* __restrict__ ad2,
    const float* __restrict__ b2, float* __restrict__ out){
  __shared__ float eC[NPB2][CAPN+1];
  __shared__ int   sC[NPB2][CAPN+1];
  int t = threadIdx.x;
  int g = t >> 5, l = t & 31;
  int n = blockIdx.x*NPB2 + g;
  if (n >= N_NODES) return;
  int beg = rowptr[n], end = rowptr[n+1];
  int deg = end - beg;
  float adv = ad2[n];
  bool cached = (deg <= CAPN);

  // phase A
  float ss = 0.f, la = 0.f;
  for (int i = l; i < deg; i += 32){
    uint2 r = erec[(size_t)beg + i];
    int s = r.x & 0xFFFFu;
    float al2 = h2f(r.x >> 16);
    float e = expf(lrelu(as2[s] + adv + al2));
    if (cached){ sC[g][i] = s * OUT_C; eC[g][i] = e; }
    ss += e; la += al2;
  }
  #pragma unroll
  for (int off = 1; off < 32; off <<= 1){
    ss += __shfl_xor(ss, off);
    la += __shfl_xor(la, off);
  }
  float inv = 1.f / fmaxf((float)deg, 1.f);
  float sl = lrelu(as2[n] + adv + la*inv);
  float es = expf(sl);
  float S = ss + es + 1e-16f;

  // phase B: lanes 0..19 own cols {2l, 2l+1}
  float a0 = 0.f, a1 = 0.f;
  if (l < 20){
    if (cached){
      for (int k = 0; k < deg; k++){
        float e = eC[g][k];
        unsigned u = *(const unsigned*)&xh2b[sC[g][k] + l*2];
        a0 += e*bfl(u); a1 += e*bfh(u);
      }
    } else {
      for (int k = 0; k < deg; k++){
        uint2 rr = erec[(size_t)beg + k];
        int s = rr.x & 0xFFFFu;
        float e = expf(lrelu(as2[s] + adv + h2f(rr.x >> 16)));
        unsigned u = *(const unsigned*)&xh2b[(size_t)s*OUT_C + l*2];
        a0 += e*bfl(u); a1 += e*bfh(u);
      }
    }
  }
  float o0 = -INFINITY, o1 = -INFINITY;
  if (l < 20){
    unsigned u = *(const unsigned*)&xh2b[(size_t)n*OUT_C + l*2];
    o0 = (a0 + es*bfl(u)) / S + b2[l*2 + 0];
    o1 = (a1 + es*bfh(u)) / S + b2[l*2 + 1];
  }
  // log_softmax over 40 cols (2 per lane in lanes 0..19)
  float mm = fmaxf(o0, o1);
  #pragma unroll
  for (int off = 1; off < 32; off <<= 1) mm = fmaxf(mm, __shfl_xor(mm, off));
  float e = (l < 20) ? (expf(o0 - mm) + expf(o1 - mm)) : 0.f;
  #pragma unroll
  for (int off = 1; off < 32; off <<= 1) e += __shfl_xor(e, off);
  if (l < 20){
    float lse = logf(e);
    out[(size_t)n*OUT_C + l*2 + 0] = o0 - mm - lse;
    out[(size_t)n*OUT_C + l*2 + 1] = o1 - mm - lse;
  }
}

// ---------------- host launcher ----------------
extern "C" void kernel_launch(void* const* d_in, const int* in_sizes, int n_in,
                              void* d_out, int out_size, void* d_ws, size_t ws_size,
                              hipStream_t stream){
  const float* x        = (const float*)d_in[0];
  const int*   ei       = (const int*)  d_in[1];
  const float* eattr    = (const float*)d_in[2];
  const float* W1       = (const float*)d_in[3];
  const float* att_src1 = (const float*)d_in[4];
  const float* att_dst1 = (const float*)d_in[5];
  const float* We1      = (const float*)d_in[6];
  const float* att_e1   = (const float*)d_in[7];
  const float* b1       = (const float*)d_in[8];
  const float* W2       = (const float*)d_in[9];
  const float* att_src2 = (const float*)d_in[10];
  const float* att_dst2 = (const float*)d_in[11];
  const float* We2      = (const float*)d_in[12];
  const float* att_e2   = (const float*)d_in[13];
  const float* b2       = (const float*)d_in[14];
  const int* src = ei;
  const int* dst = ei + N_EDGES;

  float* wsf    = (float*)d_ws;
  int*   cnt     = (int*)(wsf + O_CNT);
  int*   rank    = (int*)(wsf + O_RANK);
  int*   rowptr  = (int*)(wsf + O_ROWPTR);
  int*   stmp    = (int*)(wsf + O_STMP);
  int*   bsum    = (int*)(wsf + O_BSUM);
  int*   boff    = (int*)(wsf + O_BOFF);
  uint2* erec    = (uint2*)(wsf + O_EREC);
  float* weatt   = wsf + O_WEATT;
  unsigned short* xhb  = (unsigned short*)(wsf + O_XHB);
  float* as1     = wsf + O_AS1;
  float* ad1     = wsf + O_AD1;
  unsigned short* h1b  = (unsigned short*)(wsf + O_H1B);
  unsigned short* xh2b = (unsigned short*)(wsf + O_XH2B);
  float* as2     = wsf + O_AS2;
  float* ad2     = wsf + O_AD2;
  float* out     = (float*)d_out;

  const int NZ = (int)O_ZERO_END;
  const int EB = (N_EDGES + 255) / 256;

  k_zero   <<<(NZ + 255)/256, 256, 0, stream>>>(cnt, NZ);
  k_count  <<<EB, 256, 0, stream>>>(dst, cnt, rank);
  k_scan1  <<<SCAN_NB, SCAN_B, 0, stream>>>(cnt, stmp, bsum);
  k_scan2  <<<1, SCAN_B, 0, stream>>>(bsum, boff, We1, att_e1, We2, att_e2, weatt);
  k_scan3  <<<SCAN_NB, SCAN_B, 0, stream>>>(stmp, boff, rowptr);
  k_scatter<<<EB, 256, 0, stream>>>(src, dst, rank, eattr, rowptr, weatt, erec);

  k_gemm1  <<<(N_NODES + 63)/64, 256, 0, stream>>>(x, W1, att_src1, att_dst1, xhb, as1, ad1);
  k_agg1   <<<(N_NODES + NPB1 - 1)/NPB1, 256, 0, stream>>>(xhb, rowptr, erec, as1, ad1, b1, h1b);

  k_gemm2  <<<(N_NODES + 63)/64, 256, 0, stream>>>(h1b, W2, att_src2, att_dst2, xh2b, as2, ad2);
  k_agg2   <<<(N_NODES + NPB2 - 1)/NPB2, 256, 0, stream>>>(xh2b, rowptr, erec, as2, ad2, b2, out);
}

// Round 14
// 161.455 us; speedup vs baseline: 1.1895x; 1.0353x over previous
//
#include <hip/hip_runtime.h>
#include <hip/hip_fp16.h>
#include <math.h>

#define N_NODES 50000
#define N_EDGES 800000
#define F_IN    128
#define HID     64
#define HEADS   2
#define C1      128   // HEADS*HID
#define OUT_C   40
#define EDIM    5
#define NEG_SLOPE 0.2f
#define CAPN    64    // per-node LDS edge cache (Poisson(16): P(deg>64)~1e-20; fallback kept)
#define NPB1    16    // nodes per block, layer-1 agg (16 lanes/node)
#define NPB2    8     // nodes per block, layer-2 agg (32 lanes/node)
#define SCAN_B  256
#define SCAN_NB ((N_NODES + SCAN_B - 1) / SCAN_B)   // 196
#define G1B     ((N_NODES + 63) / 64)               // 782 gemm1 blocks
#define EB      ((N_EDGES + 255) / 256)             // 3125 edge blocks

typedef __bf16 bf16x8 __attribute__((ext_vector_type(8)));
typedef float  f32x4v __attribute__((ext_vector_type(4)));

// ---------------- workspace layout (element offsets, 4B units) ----------------
constexpr size_t pad64(size_t n){ return (n + 63) / 64 * 64; }
constexpr size_t O_CNT      = 0;
constexpr size_t O_ZERO_END = O_CNT      + pad64(N_NODES);
constexpr size_t O_RANK     = O_ZERO_END;
constexpr size_t O_STMP     = O_RANK     + pad64(N_EDGES);
constexpr size_t O_BSUM     = O_STMP     + pad64(N_NODES);
constexpr size_t O_BOFF     = O_BSUM     + pad64(SCAN_NB);
constexpr size_t O_EREC     = O_BOFF     + pad64(SCAN_NB);    // uint2 per edge {src|l2h, l0h|l1h}
constexpr size_t O_WEATT    = O_EREC     + pad64((size_t)N_EDGES*2);
constexpr size_t O_XHB      = O_WEATT    + 64;                       // bf16 [N][128]
constexpr size_t O_AS1      = O_XHB      + pad64((size_t)N_NODES*C1/2);
constexpr size_t O_AD1      = O_AS1      + pad64((size_t)N_NODES*2);
constexpr size_t O_H1B      = O_AD1      + pad64((size_t)N_NODES*2);   // bf16 [N][128]
constexpr size_t O_XH2B     = O_H1B      + pad64((size_t)N_NODES*C1/2); // bf16 [N][40]
constexpr size_t O_AS2      = O_XH2B     + pad64((size_t)N_NODES*OUT_C/2);
constexpr size_t O_AD2      = O_AS2      + pad64(N_NODES);

__device__ __forceinline__ float lrelu(float v){ return v >= 0.f ? v : NEG_SLOPE*v; }
__device__ __forceinline__ float bfl(unsigned u){ return __uint_as_float(u << 16); }
__device__ __forceinline__ float bfh(unsigned u){ return __uint_as_float(u & 0xFFFF0000u); }
__device__ __forceinline__ unsigned short f2bf(float f){
  unsigned u = __float_as_uint(f);
  return (unsigned short)((u + 0x7FFFu + ((u >> 16) & 1u)) >> 16);   // RNE
}
__device__ __forceinline__ unsigned f2h(float f){
  return (unsigned)__half_as_ushort(__float2half(f));
}
__device__ __forceinline__ float h2f(unsigned u){
  return __half2float(__ushort_as_half((unsigned short)(u & 0xFFFFu)));
}
// inline rowptr from scan pieces: rowptr[d] = d ? stmp[d-1]+boff[(d-1)>>8] : 0
__device__ __forceinline__ int rowptr_at(const int* __restrict__ stmp,
                                         const int* __restrict__ boff, int d){
  return d ? (stmp[d-1] + boff[(d-1) >> 8]) : 0;
}

// ---------------- K0: zero cnt + compute weatt (fused; rocclr fill is pathologically slow) ----
__global__ void k_init(int* __restrict__ p, int n,
                       const float* __restrict__ We1, const float* __restrict__ ae1,
                       const float* __restrict__ We2, const float* __restrict__ ae2,
                       float* __restrict__ weatt){
  int i = blockIdx.x*blockDim.x + threadIdx.x;
  if (i < n) p[i] = 0;
  if (blockIdx.x == 0){
    int t = threadIdx.x;
    if (t < 10){
      int k = t >> 1, h = t & 1;
      float s = 0.f;
      for (int c = 0; c < HID; c++) s += We1[k*C1 + h*HID + c] * ae1[h*HID + c];
      weatt[k*2 + h] = s;
    } else if (t < 15){
      int k = t - 10;
      float s = 0.f;
      for (int c = 0; c < OUT_C; c++) s += We2[k*OUT_C + c] * ae2[c];
      weatt[10 + k] = s;
    }
  }
}

// ---------------- K1: fused {in-degree+rank} || {xh1 = x @ W1 MFMA + att1} ----------------
// blocks [0, EB): count edges; blocks [EB, EB+G1B): gemm1 — independent work overlapped.
__global__ void __launch_bounds__(256) k_count_gemm1(
    const int* __restrict__ dst, int* __restrict__ cnt, int* __restrict__ rank,
    const float* __restrict__ x, const float* __restrict__ W,
    const float* __restrict__ a_src, const float* __restrict__ a_dst,
    unsigned short* __restrict__ xhb, float* __restrict__ as_o, float* __restrict__ ad_o){
  __shared__ __align__(16) unsigned char smem[128*136*2];     // 34816 B (gemm1 path)
  int bid = blockIdx.x;
  if (bid < EB){
    int e = bid*256 + threadIdx.x;
    if (e < N_EDGES) rank[e] = atomicAdd(&cnt[dst[e]], 1);
    return;
  }
  // ---- gemm1 path ----
  __bf16 (*wt)[136] = (__bf16(*)[136])smem;                   // W^T bf16: wt[col][k]
  float  (*eps)[132] = (float(*)[132])smem;                   // epilogue f32 [64][132]
  int tid = threadIdx.x;
  int wv = tid >> 6, L = tid & 63;
  int g = L >> 4, c16 = L & 15;
  int r0 = (bid - EB) * 64;

  for (int i = tid; i < F_IN*C1; i += 256){
    int k = i >> 7, c = i & 127;
    wt[c][k] = (__bf16)W[i];
  }
  __syncthreads();

  f32x4v acc[8];
  #pragma unroll
  for (int ct = 0; ct < 8; ct++) acc[ct] = (f32x4v){0.f, 0.f, 0.f, 0.f};

  int arow = r0 + wv*16 + c16;
  bool aok = arow < N_NODES;
  const float* xrow = &x[(size_t)arow*F_IN];
  #pragma unroll
  for (int ks = 0; ks < 4; ks++){
    int k0 = ks*32 + g*8;
    bf16x8 a;
    if (aok){
      float4 v0 = *(const float4*)&xrow[k0];
      float4 v1 = *(const float4*)&xrow[k0 + 4];
      a[0]=(__bf16)v0.x; a[1]=(__bf16)v0.y; a[2]=(__bf16)v0.z; a[3]=(__bf16)v0.w;
      a[4]=(__bf16)v1.x; a[5]=(__bf16)v1.y; a[6]=(__bf16)v1.z; a[7]=(__bf16)v1.w;
    } else {
      a = (bf16x8)(__bf16)0.f;
    }
    #pragma unroll
    for (int ct = 0; ct < 8; ct++){
      bf16x8 b = *(const bf16x8*)&wt[ct*16 + c16][k0];
      acc[ct] = __builtin_amdgcn_mfma_f32_16x16x32_bf16(a, b, acc[ct], 0, 0, 0);
    }
  }
  __syncthreads();   // all wt reads done; reuse LDS as epilogue buffer

  #pragma unroll
  for (int ct = 0; ct < 8; ct++){
    #pragma unroll
    for (int r = 0; r < 4; r++)
      eps[wv*16 + g*4 + r][ct*16 + c16] = acc[ct][r];
  }
  __syncthreads();

  int row = tid >> 2, cb = tid & 3;
  int grow = r0 + row;
  float vals[32];
  #pragma unroll
  for (int j = 0; j < 32; j++) vals[j] = eps[row][cb*32 + j];
  if (grow < N_NODES){
    unsigned pk[16];
    #pragma unroll
    for (int j = 0; j < 16; j++)
      pk[j] = (unsigned)f2bf(vals[2*j]) | ((unsigned)f2bf(vals[2*j+1]) << 16);
    uint4* d4 = (uint4*)&xhb[(size_t)grow*C1 + cb*32];
    d4[0] = make_uint4(pk[0],pk[1],pk[2],pk[3]);
    d4[1] = make_uint4(pk[4],pk[5],pk[6],pk[7]);
    d4[2] = make_uint4(pk[8],pk[9],pk[10],pk[11]);
    d4[3] = make_uint4(pk[12],pk[13],pk[14],pk[15]);
  }
  float s = 0.f, d = 0.f;
  #pragma unroll
  for (int j = 0; j < 32; j++){
    s += vals[j]*a_src[cb*32 + j];
    d += vals[j]*a_dst[cb*32 + j];
  }
  s += __shfl_xor(s, 1);
  d += __shfl_xor(d, 1);
  if ((cb & 1) == 0 && grow < N_NODES){
    int h = cb >> 1;
    as_o[grow*2 + h] = s;
    ad_o[grow*2 + h] = d;
  }
}

// ---------------- K2: device-wide exclusive scan, 2 wide dispatches ----------------
__global__ void __launch_bounds__(SCAN_B) k_scan1(const int* __restrict__ cnt,
                                                  int* __restrict__ stmp,
                                                  int* __restrict__ bsum){
  int blk = blockIdx.x, t = threadIdx.x;
  int i = blk*SCAN_B + t;
  int v = (i < N_NODES) ? cnt[i] : 0;
  int lane = t & 63, w = t >> 6;
  int x = v;
  #pragma unroll
  for (int off = 1; off < 64; off <<= 1){
    int y = __shfl_up(x, off);
    if (lane >= off) x += y;
  }
  __shared__ int wsum[SCAN_B/64];
  if (lane == 63) wsum[w] = x;
  __syncthreads();
  int add = 0;
  for (int k = 0; k < w; k++) add += wsum[k];
  x += add;
  if (i < N_NODES) stmp[i] = x;
  if (t == SCAN_B-1) bsum[blk] = x;
}

__global__ void __launch_bounds__(SCAN_B) k_scan2(const int* __restrict__ bsum,
                                                  int* __restrict__ boff){
  int t = threadIdx.x;
  int v = (t < SCAN_NB) ? bsum[t] : 0;
  int lane = t & 63, w = t >> 6;
  int x = v;
  #pragma unroll
  for (int off = 1; off < 64; off <<= 1){
    int y = __shfl_up(x, off);
    if (lane >= off) x += y;
  }
  __shared__ int wsum[SCAN_B/64];
  if (lane == 63) wsum[w] = x;
  __syncthreads();
  int add = 0;
  for (int k = 0; k < w; k++) add += wsum[k];
  x += add;                      // inclusive
  if (t < SCAN_NB) boff[t] = x - v;  // exclusive
}

// ---------------- K3: scatter edges into CSR, atomic-free, 8B packed records ----------------
__global__ void k_scatter(const int* __restrict__ src, const int* __restrict__ dst,
                          const int* __restrict__ rank,
                          const float* __restrict__ eattr,
                          const int* __restrict__ stmp, const int* __restrict__ boff,
                          const float* __restrict__ weatt,
                          uint2* __restrict__ erec){
  int e = blockIdx.x*blockDim.x + threadIdx.x;
  if (e >= N_EDGES) return;
  int d = dst[e];
  int pos = rowptr_at(stmp, boff, d) + rank[e];
  float a[EDIM];
  #pragma unroll
  for (int k = 0; k < EDIM; k++) a[k] = eattr[e*EDIM + k];
  float l0 = 0.f, l1 = 0.f, l2 = 0.f;
  #pragma unroll
  for (int k = 0; k < EDIM; k++){
    l0 += a[k]*weatt[k*2 + 0];
    l1 += a[k]*weatt[k*2 + 1];
    l2 += a[k]*weatt[10 + k];
  }
  unsigned w0 = (unsigned)src[e] | (f2h(l2) << 16);
  unsigned w1 = f2h(l0) | (f2h(l1) << 16);
  erec[pos] = make_uint2(w0, w1);
}

// ---------------- K7: layer-1 aggregation; 16 lanes per node, no barriers; bf16 h1 out ----------------
__global__ void __launch_bounds__(256) k_agg1(const unsigned short* __restrict__ xhb,
    const int* __restrict__ stmp, const int* __restrict__ boff,
    const uint2* __restrict__ erec,
    const float* __restrict__ as1, const float* __restrict__ ad1,
    const float* __restrict__ b1, unsigned short* __restrict__ h1b){
  __shared__ float2 eC[NPB1][CAPN+1];   // interleaved (e0,e1) — padded row kills bank conflicts
  __shared__ int    sC[NPB1][CAPN+1];
  int t = threadIdx.x;
  int g = t >> 4, l = t & 15;
  int n = blockIdx.x*NPB1 + g;
  if (n >= N_NODES) return;
  int beg = rowptr_at(stmp, boff, n);
  int end = stmp[n] + boff[n >> 8];
  int deg = end - beg;
  float2 adn = *(const float2*)&ad1[n*2];
  bool cached = (deg <= CAPN);

  // phase A: exp(logit) -> LDS (group-local), sums via 4-step shuffle
  float s0 = 0.f, s1 = 0.f, la0 = 0.f, la1 = 0.f;
  for (int i = l; i < deg; i += 16){
    uint2 r = erec[(size_t)beg + i];
    int s = r.x & 0xFFFFu;
    float al0 = h2f(r.y), al1 = h2f(r.y >> 16);
    float2 a = *(const float2*)&as1[s*2];
    float e0 = expf(lrelu(a.x + adn.x + al0));
    float e1 = expf(lrelu(a.y + adn.y + al1));
    if (cached){ sC[g][i] = s * C1; eC[g][i] = make_float2(e0, e1); }
    s0 += e0; s1 += e1; la0 += al0; la1 += al1;
  }
  #pragma unroll
  for (int off = 1; off < 16; off <<= 1){
    s0 += __shfl_xor(s0, off); s1 += __shfl_xor(s1, off);
    la0 += __shfl_xor(la0, off); la1 += __shfl_xor(la1, off);
  }
  float inv = 1.f / fmaxf((float)deg, 1.f);
  float2 asn = *(const float2*)&as1[n*2];
  float sl0 = lrelu(asn.x + adn.x + la0*inv);
  float sl1 = lrelu(asn.y + adn.y + la1*inv);
  float es0 = expf(sl0), es1 = expf(sl1);
  float S0 = s0 + es0 + 1e-16f;
  float S1 = s1 + es1 + 1e-16f;

  // phase B: per edge — e broadcast from LDS, 16 lanes x 16B coalesced row
  int head = l >> 3;                   // lane 0..7 head0 (cols 0..63), 8..15 head1
  float acc[8];
  #pragma unroll
  for (int j = 0; j < 8; j++) acc[j] = 0.f;
  if (cached){
    for (int k = 0; k < deg; k++){
      float2 e2 = eC[g][k];
      float e = head ? e2.y : e2.x;
      uint4 r = *(const uint4*)&xhb[sC[g][k] + l*8];
      acc[0] += e*bfl(r.x); acc[1] += e*bfh(r.x);
      acc[2] += e*bfl(r.y); acc[3] += e*bfh(r.y);
      acc[4] += e*bfl(r.z); acc[5] += e*bfh(r.z);
      acc[6] += e*bfl(r.w); acc[7] += e*bfh(r.w);
    }
  } else {
    // fallback (deg > CAPN): recompute e per edge, group-local, ~never taken
    for (int k = 0; k < deg; k++){
      uint2 rr = erec[(size_t)beg + k];
      int s = rr.x & 0xFFFFu;
      float2 a = *(const float2*)&as1[s*2];
      float e = head ? expf(lrelu(a.y + adn.y + h2f(rr.y >> 16)))
                     : expf(lrelu(a.x + adn.x + h2f(rr.y)));
      uint4 r = *(const uint4*)&xhb[(size_t)s*C1 + l*8];
      acc[0] += e*bfl(r.x); acc[1] += e*bfh(r.x);
      acc[2] += e*bfl(r.y); acc[3] += e*bfh(r.y);
      acc[4] += e*bfl(r.z); acc[5] += e*bfh(r.z);
      acc[6] += e*bfl(r.w); acc[7] += e*bfh(r.w);
    }
  }
  // epilogue: each lane owns its 8 cols — pack to bf16, single 16B store
  float es = head ? es1 : es0;
  float den = head ? S1 : S0;
  uint4 r = *(const uint4*)&xhb[(size_t)n*C1 + l*8];
  float xs8[8];
  xs8[0]=bfl(r.x); xs8[1]=bfh(r.x); xs8[2]=bfl(r.y); xs8[3]=bfh(r.y);
  xs8[4]=bfl(r.z); xs8[5]=bfh(r.z); xs8[6]=bfl(r.w); xs8[7]=bfh(r.w);
  unsigned pk[4];
  #pragma unroll
  for (int p = 0; p < 4; p++){
    float v0 = (acc[2*p]   + es*xs8[2*p])   / den + b1[l*8 + 2*p];
    float v1 = (acc[2*p+1] + es*xs8[2*p+1]) / den + b1[l*8 + 2*p+1];
    v0 = v0 > 0.f ? v0 : expm1f(v0);   // ELU
    v1 = v1 > 0.f ? v1 : expm1f(v1);
    pk[p] = (unsigned)f2bf(v0) | ((unsigned)f2bf(v1) << 16);
  }
  *(uint4*)&h1b[(size_t)n*C1 + l*8] = make_uint4(pk[0], pk[1], pk[2], pk[3]);
}

// ---------------- K8: xh2 = h1 @ W2 via MFMA bf16 (fused att2, bf16 out) ----------------
__global__ void __launch_bounds__(256) k_gemm2(const unsigned short* __restrict__ h1b,
    const float* __restrict__ W2, const float* __restrict__ a_src2,
    const float* __restrict__ a_dst2,
    unsigned short* __restrict__ xh2b, float* __restrict__ as_o, float* __restrict__ ad_o){
  __shared__ __align__(16) unsigned char smem[64*52*4];        // 13312 B
  __bf16 (*wt)[136] = (__bf16(*)[136])smem;                    // W2^T bf16 [48][136] = 13056 B
  float  (*eps)[52] = (float(*)[52])smem;                      // epilogue f32 [64][52]
  int tid = threadIdx.x;
  int wv = tid >> 6, L = tid & 63;
  int g = L >> 4, c16 = L & 15;
  int r0 = blockIdx.x * 64;

  for (int i = tid; i < 48*F_IN; i += 256){
    int c = i >> 7, k = i & 127;
    wt[c][k] = (c < OUT_C) ? (__bf16)W2[k*OUT_C + c] : (__bf16)0.f;
  }
  __syncthreads();

  f32x4v acc[3];
  #pragma unroll
  for (int ct = 0; ct < 3; ct++) acc[ct] = (f32x4v){0.f, 0.f, 0.f, 0.f};

  int arow = r0 + wv*16 + c16;
  bool aok = arow < N_NODES;
  const unsigned short* hrow = &h1b[(size_t)arow*C1];
  #pragma unroll
  for (int ks = 0; ks < 4; ks++){
    int k0 = ks*32 + g*8;
    bf16x8 a;
    if (aok) a = *(const bf16x8*)&hrow[k0];
    else     a = (bf16x8)(__bf16)0.f;
    #pragma unroll
    for (int ct = 0; ct < 3; ct++){
      bf16x8 b = *(const bf16x8*)&wt[ct*16 + c16][k0];
      acc[ct] = __builtin_amdgcn_mfma_f32_16x16x32_bf16(a, b, acc[ct], 0, 0, 0);
    }
  }
  __syncthreads();

  #pragma unroll
  for (int ct = 0; ct < 3; ct++){
    #pragma unroll
    for (int r = 0; r < 4; r++)
      eps[wv*16 + g*4 + r][ct*16 + c16] = acc[ct][r];
  }
  __syncthreads();

  int row = tid >> 2, cb = tid & 3;
  int grow = r0 + row;
  int base = cb*12;
  float vals[12];
  #pragma unroll
  for (int j = 0; j < 12; j++) vals[j] = eps[row][base + j];
  int npair = (cb < 3) ? 6 : 2;        // cb=3 covers cols 36..47; only 36..39 valid
  if (grow < N_NODES){
    unsigned* dp = (unsigned*)&xh2b[(size_t)grow*OUT_C + base];
    for (int jj = 0; jj < npair; jj++)
      dp[jj] = (unsigned)f2bf(vals[2*jj]) | ((unsigned)f2bf(vals[2*jj+1]) << 16);
  }
  float s = 0.f, d = 0.f;
  #pragma unroll
  for (int j = 0; j < 12; j++){
    int col = base + j;
    if (col < OUT_C){
      s += vals[j]*a_src2[col];
      d += vals[j]*a_dst2[col];
    }
  }
  s += __shfl_xor(s, 1); s += __shfl_xor(s, 2);
  d += __shfl_xor(d, 1); d += __shfl_xor(d, 2);
  if (cb == 0 && grow < N_NODES){
    as_o[grow] = s;
    ad_o[grow] = d;
  }
}

// ---------------- K10: layer-2 aggregation + log_softmax; 32 lanes per node ----------------
__global__ void __launch_bounds__(256) k_agg2(const unsigned short* __restrict__ xh2b,
    const int* __restrict__ stmp, const int* __restrict__ boff,
    const uint2* __restrict__ erec,
    const float* __restrict__ as2, const float* __restrict__ ad2,
    const float* __restrict__ b2, float* __restrict__ out){
  __shared__ float eC[NPB2][CAPN+1];
  __shared__ int   sC[NPB2][CAPN+1];
  int t = threadIdx.x;
  int g = t >> 5, l = t & 31;
  int n = blockIdx.x*NPB2 + g;
  if (n >= N_NODES) return;
  int beg = rowptr_at(stmp, boff, n);
  int end = stmp[n] + boff[n >> 8];
  int deg = end - beg;
  float adv = ad2[n];
  bool cached = (deg <= CAPN);

  // phase A
  float ss = 0.f, la = 0.f;
  for (int i = l; i < deg; i += 32){
    uint2 r = erec[(size_t)beg + i];
    int s = r.x & 0xFFFFu;
    float al2 = h2f(r.x >> 16);
    float e = expf(lrelu(as2[s] + adv + al2));
    if (cached){ sC[g][i] = s * OUT_C; eC[g][i] = e; }
    ss += e; la += al2;
  }
  #pragma unroll
  for (int off = 1; off < 32; off <<= 1){
    ss += __shfl_xor(ss, off);
    la += __shfl_xor(la, off);
  }
  float inv = 1.f / fmaxf((float)deg, 1.f);
  float sl = lrelu(as2[n] + adv + la*inv);
  float es = expf(sl);
  float S = ss + es + 1e-16f;

  // phase B: lanes 0..19 own cols {2l, 2l+1}
  float a0 = 0.f, a1 = 0.f;
  if (l < 20){
    if (cached){
      for (int k = 0; k < deg; k++){
        float e = eC[g][k];
        unsigned u = *(const unsigned*)&xh2b[sC[g][k] + l*2];
        a0 += e*bfl(u); a1 += e*bfh(u);
      }
    } else {
      for (int k = 0; k < deg; k++){
        uint2 rr = erec[(size_t)beg + k];
        int s = rr.x & 0xFFFFu;
        float e = expf(lrelu(as2[s] + adv + h2f(rr.x >> 16)));
        unsigned u = *(const unsigned*)&xh2b[(size_t)s*OUT_C + l*2];
        a0 += e*bfl(u); a1 += e*bfh(u);
      }
    }
  }
  float o0 = -INFINITY, o1 = -INFINITY;
  if (l < 20){
    unsigned u = *(const unsigned*)&xh2b[(size_t)n*OUT_C + l*2];
    o0 = (a0 + es*bfl(u)) / S + b2[l*2 + 0];
    o1 = (a1 + es*bfh(u)) / S + b2[l*2 + 1];
  }
  // log_softmax over 40 cols (2 per lane in lanes 0..19)
  float mm = fmaxf(o0, o1);
  #pragma unroll
  for (int off = 1; off < 32; off <<= 1) mm = fmaxf(mm, __shfl_xor(mm, off));
  float e = (l < 20) ? (expf(o0 - mm) + expf(o1 - mm)) : 0.f;
  #pragma unroll
  for (int off = 1; off < 32; off <<= 1) e += __shfl_xor(e, off);
  if (l < 20){
    float lse = logf(e);
    out[(size_t)n*OUT_C + l*2 + 0] = o0 - mm - lse;
    out[(size_t)n*OUT_C + l*2 + 1] = o1 - mm - lse;
  }
}

// ---------------- host launcher ----------------
extern "C" void kernel_launch(void* const* d_in, const int* in_sizes, int n_in,
                              void* d_out, int out_size, void* d_ws, size_t ws_size,
                              hipStream_t stream){
  const float* x        = (const float*)d_in[0];
  const int*   ei       = (const int*)  d_in[1];
  const float* eattr    = (const float*)d_in[2];
  const float* W1       = (const float*)d_in[3];
  const float* att_src1 = (const float*)d_in[4];
  const float* att_dst1 = (const float*)d_in[5];
  const float* We1      = (const float*)d_in[6];
  const float* att_e1   = (const float*)d_in[7];
  const float* b1       = (const float*)d_in[8];
  const float* W2       = (const float*)d_in[9];
  const float* att_src2 = (const float*)d_in[10];
  const float* att_dst2 = (const float*)d_in[11];
  const float* We2      = (const float*)d_in[12];
  const float* att_e2   = (const float*)d_in[13];
  const float* b2       = (const float*)d_in[14];
  const int* src = ei;
  const int* dst = ei + N_EDGES;

  float* wsf    = (float*)d_ws;
  int*   cnt     = (int*)(wsf + O_CNT);
  int*   rank    = (int*)(wsf + O_RANK);
  int*   stmp    = (int*)(wsf + O_STMP);
  int*   bsum    = (int*)(wsf + O_BSUM);
  int*   boff    = (int*)(wsf + O_BOFF);
  uint2* erec    = (uint2*)(wsf + O_EREC);
  float* weatt   = wsf + O_WEATT;
  unsigned short* xhb  = (unsigned short*)(wsf + O_XHB);
  float* as1     = wsf + O_AS1;
  float* ad1     = wsf + O_AD1;
  unsigned short* h1b  = (unsigned short*)(wsf + O_H1B);
  unsigned short* xh2b = (unsigned short*)(wsf + O_XH2B);
  float* as2     = wsf + O_AS2;
  float* ad2     = wsf + O_AD2;
  float* out     = (float*)d_out;

  const int NZ = (int)O_ZERO_END;

  k_init   <<<(NZ + 255)/256, 256, 0, stream>>>(cnt, NZ, We1, att_e1, We2, att_e2, weatt);
  k_count_gemm1<<<EB + G1B, 256, 0, stream>>>(dst, cnt, rank,
                                              x, W1, att_src1, att_dst1, xhb, as1, ad1);
  k_scan1  <<<SCAN_NB, SCAN_B, 0, stream>>>(cnt, stmp, bsum);
  k_scan2  <<<1, SCAN_B, 0, stream>>>(bsum, boff);
  k_scatter<<<EB, 256, 0, stream>>>(src, dst, rank, eattr, stmp, boff, weatt, erec);

  k_agg1   <<<(N_NODES + NPB1 - 1)/NPB1, 256, 0, stream>>>(xhb, stmp, boff, erec,
                                                           as1, ad1, b1, h1b);
  k_gemm2  <<<(N_NODES + 63)/64, 256, 0, stream>>>(h1b, W2, att_src2, att_dst2, xh2b, as2, ad2);
  k_agg2   <<<(N_NODES + NPB2 - 1)/NPB2, 256, 0, stream>>>(xh2b, stmp, boff, erec,
                                                           as2, ad2, b2, out);
}